// Round 8
// baseline (244.850 us; speedup 1.0000x reference)
//
#include <hip/hip_runtime.h>
#include <stdint.h>

typedef __attribute__((ext_vector_type(4))) float f32x4;
typedef __attribute__((ext_vector_type(8))) short s16x8;

#define BB 4
#define NN 4096
#define FF 32
#define BNF (BB*NN*FF)   // 524288

typedef __attribute__((address_space(3))) void       as3_void;
typedef const __attribute__((address_space(1))) void as1_cvoid;

// ---------- bf16 helpers ----------
static __device__ __forceinline__ float bf2f(uint16_t u) {
    union { uint32_t i; float f; } v; v.i = ((uint32_t)u) << 16; return v.f;
}
static __device__ __forceinline__ uint16_t f2bf(float f) {
    union { float f; uint32_t i; } v; v.f = f;
    uint32_t r = v.i + 0x7FFFu + ((v.i >> 16) & 1u);
    return (uint16_t)(r >> 16);
}
static __device__ __forceinline__ float sig_acc(float x) { return 1.0f / (1.0f + expf(-x)); }

// ======================================================================
// prep: ONE launch for all input-only work.  (unchanged)
// ======================================================================
__global__ __launch_bounds__(256) void prep_kernel(
    const float* __restrict__ adj, uint16_t* __restrict__ adjb, int cvtN,
    const float* __restrict__ Wf, uint16_t* __restrict__ Wp,
    const float* __restrict__ x, const float* __restrict__ h,
    const float* __restrict__ m,
    uint16_t* __restrict__ P, uint16_t* __restrict__ P2)
{
    int bid = blockIdx.x;
    int t = threadIdx.x;

    if (bid < cvtN) {
        size_t i = ((size_t)bid * 256 + t) * 8;
        float4 v0 = *(const float4*)(adj + i);
        float4 v1 = *(const float4*)(adj + i + 4);
        union { uint4 u; uint16_t e[8]; } o;
        o.e[0] = f2bf(v0.x); o.e[1] = f2bf(v0.y); o.e[2] = f2bf(v0.z); o.e[3] = f2bf(v0.w);
        o.e[4] = f2bf(v1.x); o.e[5] = f2bf(v1.y); o.e[6] = f2bf(v1.z); o.e[7] = f2bf(v1.w);
        *(uint4*)(adjb + i) = o.u;
        return;
    }
    bid -= cvtN;

    if (bid < 112) {
        // W: fp32 [14][32][64] -> bf16 Wp[gp][col][slot^swz][k&7]
        // B-frag (16x16x32): lane l holds B[k=(l>>4)*8+e][col=l&15].
        int idx = bid * 256 + t;                    // 14*32*64 = 28672
        int g   = idx >> 11;
        int k   = (idx >> 6) & 31;
        int col = idx & 63;
        uint16_t v = f2bf(Wf[idx]);                 // Wf[g][k][col]
        int gp = g >> 1;
        int sl = ((g & 1) << 2) | (k >> 3);
        int ph = sl ^ (col & 7);
        Wp[((gp * 64 + col) * 64) + ph * 8 + (k & 7)] = v;
        return;
    }
    bid -= 112;

    // pack: state [B][N][F] fp32 -> dst[rowbase + b*32 + f][n] bf16
    const float* src; uint16_t* dst; int rowbase, b, n0;
    if (bid < 512) {
        int tensor = bid >> 8;
        src = tensor ? h : x; dst = P; rowbase = tensor * 128;
        b = (bid >> 6) & 3; n0 = (bid & 63) * 64;
    } else {
        int q = bid - 512;
        src = m; dst = P2; rowbase = 128;
        b = q >> 6; n0 = (q & 63) * 64;
    }
    __shared__ uint16_t tl[32][65];
    {
        int i = t >> 2, ch = t & 3;       // node i (0..63), f-chunk ch (8 floats)
        size_t idx = ((size_t)(b * NN + n0 + i)) * FF + ch * 8;
        float4 v0 = *(const float4*)(src + idx);
        float4 v1 = *(const float4*)(src + idx + 4);
        uint16_t e[8] = { f2bf(v0.x), f2bf(v0.y), f2bf(v0.z), f2bf(v0.w),
                          f2bf(v1.x), f2bf(v1.y), f2bf(v1.z), f2bf(v1.w) };
        #pragma unroll
        for (int k = 0; k < 8; k++) tl[ch * 8 + k][i] = e[k];
    }
    __syncthreads();
    {
        int f = t >> 3, ch = t & 7;
        union { uint4 u; uint16_t e[8]; } v;
        #pragma unroll
        for (int k = 0; k < 8; k++) v.e[k] = tl[f][ch * 8 + k];
        size_t row = (size_t)(rowbase + b * 32 + f);
        *(uint4*)(dst + row * NN + n0 + ch * 8) = v.u;
    }
}

// ---------- GEMM: Cb[c][m] = bf16( sum_k adj[m][k] * Bt[c][k] ) ----------
// Full-K, direct bf16 output (no split-K partials).
// Grid (nt=2, mt=128): M-tile 32, C-tile 128 -> 256 blocks (1/CU).
// nt pairs are grid-adjacent -> same XCD -> A-tile shared in L2; B (2 MB)
// is L2-resident chip-wide.  4 waves: wave w owns c-sub w*32..+31.
// Same validated 64B-row XOR swizzle + global_load_lds staging.
__global__ __launch_bounds__(256) void gemm_kernel(
    const void* __restrict__ Av,      // adj: bf16 (isf32A=0) or fp32 (isf32A=1)
    const uint16_t* __restrict__ Bt,  // [256][4096] bf16
    uint16_t* __restrict__ Cb,        // [256][4096] bf16
    int isf32A)
{
    int nt = blockIdx.x, mt = blockIdx.y;
    int m0 = mt * 32, c0 = nt * 128;
    __shared__ __align__(16) uint16_t aL[32 * 32];    // 2 KB
    __shared__ __align__(16) uint16_t bL[128 * 32];   // 8 KB
    int t = threadIdx.x;
    int lane = t & 63, w = t >> 6;
    int lm = lane & 15, lk = lane >> 4;

    const uint16_t* A16 = (const uint16_t*)Av;
    const float*    Af  = (const float*)Av;

    f32x4 acc[2][2] = {};

    for (int kk = 0; kk < 4096; kk += 32) {
        if (!isf32A) {
            if (t < 128) {                                // A tile: 128 x 16B
                int pos  = t * 16;
                int row  = pos >> 6;
                int slot = ((pos >> 4) & 3) ^ ((row >> 1) & 3);
                size_t aidx = (size_t)(m0 + row) * 4096 + kk + slot * 8;
                __builtin_amdgcn_global_load_lds((as1_cvoid*)(A16 + aidx),
                                                 (as3_void*)((char*)aL + pos), 16, 0, 0);
            }
            #pragma unroll
            for (int q = 0; q < 2; q++) {                 // B tile: 512 x 16B
                int pos  = q * 4096 + t * 16;
                int row  = pos >> 6;
                int slot = ((pos >> 4) & 3) ^ ((row >> 1) & 3);
                size_t bidx = (size_t)(c0 + row) * 4096 + kk + slot * 8;
                __builtin_amdgcn_global_load_lds((as1_cvoid*)(Bt + bidx),
                                                 (as3_void*)((char*)bL + pos), 16, 0, 0);
            }
        } else {
            union { uint4 u; uint16_t e[8]; } sa, sb[2];
            int apos = t * 16, arow = apos >> 6;
            if (t < 128) {
                int slot = ((apos >> 4) & 3) ^ ((arow >> 1) & 3);
                size_t aidx = (size_t)(m0 + arow) * 4096 + kk + slot * 8;
                union { uint4 u[2]; float f[8]; } va;
                va.u[0] = *(const uint4*)(Af + aidx);
                va.u[1] = *(const uint4*)(Af + aidx + 4);
                #pragma unroll
                for (int k = 0; k < 8; k++) sa.e[k] = f2bf(va.f[k]);
            }
            #pragma unroll
            for (int q = 0; q < 2; q++) {
                int pos  = q * 4096 + t * 16;
                int row  = pos >> 6;
                int slot = ((pos >> 4) & 3) ^ ((row >> 1) & 3);
                size_t bidx = (size_t)(c0 + row) * 4096 + kk + slot * 8;
                sb[q].u = *(const uint4*)(Bt + bidx);
            }
            if (t < 128) *(uint4*)((char*)aL + apos) = sa.u;
            #pragma unroll
            for (int q = 0; q < 2; q++)
                *(uint4*)((char*)bL + q * 4096 + t * 16) = sb[q].u;
        }
        __syncthreads();
        s16x8 af[2], bfr[2];
        #pragma unroll
        for (int i = 0; i < 2; i++) {
            int r = i * 16 + lm;
            af[i] = *(const s16x8*)(aL + r * 32 + ((lk ^ ((r >> 1) & 3)) * 8));
        }
        #pragma unroll
        for (int j = 0; j < 2; j++) {
            int r = w * 32 + j * 16 + lm;
            bfr[j] = *(const s16x8*)(bL + r * 32 + ((lk ^ ((r >> 1) & 3)) * 8));
        }
        #pragma unroll
        for (int i = 0; i < 2; i++)
            #pragma unroll
            for (int j = 0; j < 2; j++)
                acc[i][j] = __builtin_amdgcn_mfma_f32_16x16x32_bf16(af[i], bfr[j], acc[i][j], 0, 0, 0);
        __syncthreads();
    }

    // C/D layout: col=lane&15 (c dim), row=(lane>>4)*4+reg (m dim)
    int r4 = (lane >> 4) * 4;
    #pragma unroll
    for (int i = 0; i < 2; i++)
        #pragma unroll
        for (int j = 0; j < 2; j++) {
            int c = c0 + w * 32 + j * 16 + lm;
            int mr = m0 + i * 16 + r4;
            union { uint2 u; uint16_t e[4]; } v;
            #pragma unroll
            for (int r = 0; r < 4; r++) v.e[r] = f2bf(acc[i][j][r]);
            *(uint2*)(Cb + (size_t)c * 4096 + mr) = v.u;
        }
}

// ======================================================================
// fuse1: 1024 blocks x 256 threads (4 waves); block = (batch b, 16 nodes).
// Phase 1: cooperative load of Cbuf (bf16).
// Phase 2: all waves build identical A-frags; wave w computes gate-pair w
//          (B-frags direct from global Wp, L2-broadcast) -> GLU -> SX.
// Phase 3: all 256 threads do the LSTM update from SX; pack h1 -> P2.
// ======================================================================
__global__ __launch_bounds__(256) void fuse1_kernel(
    const uint16_t* __restrict__ Cbi, // [256][4096] bf16
    const uint16_t* __restrict__ Wp,  // packed W (prep)
    const float* __restrict__ bf_,
    const float* __restrict__ cf,
    float* __restrict__ cnew, uint16_t* __restrict__ S2t)
{
    __shared__ float    AL[64 * 17];   // [c'][node 0..15], pitch 17
    __shared__ float    SX[4][64][9];  // per-gate-pair GLU outputs (pad 9)
    __shared__ uint16_t H1[32 * 18];   // [f][node]

    int t = threadIdx.x;
    int bid = blockIdx.x;              // 1024
    int b = bid >> 8, n0 = (bid & 255) * 16;
    int lane = t & 63, w = t >> 6;
    int j = lane & 15, kg = lane >> 4;
    int ej = t & 15, erow = (t >> 4) & 15;   // element coords for phase 3

    // c prefetch for phase 3 (in flight under phase 1)
    float cv[2];
    #pragma unroll
    for (int hh = 0; hh < 2; hh++)
        cv[hh] = cf[((size_t)(b * NN + n0 + erow)) * FF + ej + hh * 16];

    // phase 1: load Cbuf. thread t -> c'-row r = t>>2, chunk ch = t&3.
    {
        int r = t >> 2, ch = t & 3;
        int crow = (r < 32) ? (b * 32 + r) : (128 + b * 32 + (r - 32));
        const uint16_t* cp = Cbi + (size_t)crow * 4096 + n0 + ch * 4;
        uint2 v = *(const uint2*)cp;
        const uint16_t* pe = (const uint16_t*)&v;
        #pragma unroll
        for (int e = 0; e < 4; e++) AL[r * 17 + ch * 4 + e] = bf2f(pe[e]);
    }
    __syncthreads();

    // phase 2: A frags (identical in every wave); wave w = gate-pair w
    s16x8 a_ax, a_ah;
    #pragma unroll
    for (int e = 0; e < 8; e++) {
        int k = kg * 8 + e;
        a_ax[e] = (short)f2bf(AL[k * 17 + j]);
        a_ah[e] = (short)f2bf(AL[(32 + k) * 17 + j]);
    }
    {
        int p = w;                                // gate-pair: even=ax, odd=ah
        int g0 = p * 2, g1 = p * 2 + 1;
        f32x4 ac0[4] = {}, ac1[4] = {};
        #pragma unroll
        for (int ct = 0; ct < 4; ct++) {
            int col = ct * 16 + j;
            int ph0 = (kg)     ^ (col & 7);
            int ph1 = (4 + kg) ^ (col & 7);
            s16x8 b0 = *(const s16x8*)(Wp + (p * 64 + col) * 64 + ph0 * 8);
            s16x8 b1 = *(const s16x8*)(Wp + (p * 64 + col) * 64 + ph1 * 8);
            ac0[ct] = __builtin_amdgcn_mfma_f32_16x16x32_bf16(a_ax, b0, ac0[ct], 0, 0, 0);
            ac1[ct] = __builtin_amdgcn_mfma_f32_16x16x32_bf16(a_ah, b1, ac1[ct], 0, 0, 0);
        }
        #pragma unroll
        for (int hh = 0; hh < 2; hh++)
            #pragma unroll
            for (int r = 0; r < 4; r++) {
                float z0l = ac0[hh][r]     + bf_[g0 * 64 + hh * 16 + j];
                float z0r = ac0[2 + hh][r] + bf_[g0 * 64 + 32 + hh * 16 + j];
                float z1l = ac1[hh][r]     + bf_[g1 * 64 + hh * 16 + j];
                float z1r = ac1[2 + hh][r] + bf_[g1 * 64 + 32 + hh * 16 + j];
                SX[p][lane][hh * 4 + r] = z0l * sig_acc(z0r) + z1l * sig_acc(z1r);
            }
    }
    __syncthreads();

    // phase 3: LSTM update; thread t handles element (erow, ej), hh=0,1
    {
        int pl = ((erow >> 2) << 4) | ej;         // producer lane
        int ridx = erow & 3;
        #pragma unroll
        for (int hh = 0; hh < 2; hh++) {
            float s0 = SX[0][pl][hh * 4 + ridx];
            float s1 = SX[1][pl][hh * 4 + ridx];
            float s2 = SX[2][pl][hh * 4 + ridx];
            float s3 = SX[3][pl][hh * 4 + ridx];
            float fg = sig_acc(s0), ig = sig_acc(s1);
            float cc = tanhf(s2),   og = sig_acc(s3);
            float cn = fg * cv[hh] + ig * cc;
            size_t gidx = ((size_t)(b * NN + n0 + erow)) * FF + ej + hh * 16;
            cnew[gidx] = cn;
            H1[(ej + hh * 16) * 18 + erow] = f2bf(og * tanhf(cn));
        }
    }
    __syncthreads();
    if (t < 64) {   // pack h1 -> P2 rows b*32+f (GEMM2 B operand, rows 0..127)
        int f = t >> 1, half = t & 1;
        union { uint4 u; uint16_t e[8]; } v;
        #pragma unroll
        for (int k = 0; k < 8; k++) v.e[k] = H1[f * 18 + half * 8 + k];
        *(uint4*)(S2t + ((size_t)(b * 32 + f)) * NN + n0 + half * 8) = v.u;
    }
}

// ======================================================================
// fuse2: same structure, 3 gate-pairs (waves 0..2; wave 3 idles in phase 2).
// ======================================================================
__global__ __launch_bounds__(256) void fuse2_kernel(
    const uint16_t* __restrict__ Cbi,
    const uint16_t* __restrict__ Wp,
    const float* __restrict__ bf_,
    const float* __restrict__ mf,
    float* __restrict__ hnew, float* __restrict__ mnew)
{
    __shared__ float AL[64 * 17];
    __shared__ float SX[3][64][9];

    int t = threadIdx.x;
    int bid = blockIdx.x;
    int b = bid >> 8, n0 = (bid & 255) * 16;
    int lane = t & 63, w = t >> 6;
    int j = lane & 15, kg = lane >> 4;
    int ej = t & 15, erow = (t >> 4) & 15;

    float mv[2];
    #pragma unroll
    for (int hh = 0; hh < 2; hh++)
        mv[hh] = mf[((size_t)(b * NN + n0 + erow)) * FF + ej + hh * 16];

    {
        int r = t >> 2, ch = t & 3;
        int crow = (r < 32) ? (b * 32 + r) : (128 + b * 32 + (r - 32));
        const uint16_t* cp = Cbi + (size_t)crow * 4096 + n0 + ch * 4;
        uint2 v = *(const uint2*)cp;
        const uint16_t* pe = (const uint16_t*)&v;
        #pragma unroll
        for (int e = 0; e < 4; e++) AL[r * 17 + ch * 4 + e] = bf2f(pe[e]);
    }
    __syncthreads();

    if (w < 3) {
        s16x8 a_h1, a_m;
        #pragma unroll
        for (int e = 0; e < 8; e++) {
            int k = kg * 8 + e;
            a_h1[e] = (short)f2bf(AL[k * 17 + j]);
            a_m[e]  = (short)f2bf(AL[(32 + k) * 17 + j]);
        }
        const uint16_t* WpG = Wp + 4 * 64 * 64;   // gate-pairs 4..6 (gates 8..13)
        const float*    bG  = bf_ + 512;
        int p = w;
        int g0 = p * 2, g1 = p * 2 + 1;           // even: ah1, odd: am
        f32x4 ac0[4] = {}, ac1[4] = {};
        #pragma unroll
        for (int ct = 0; ct < 4; ct++) {
            int col = ct * 16 + j;
            int ph0 = (kg)     ^ (col & 7);
            int ph1 = (4 + kg) ^ (col & 7);
            s16x8 b0 = *(const s16x8*)(WpG + (p * 64 + col) * 64 + ph0 * 8);
            s16x8 b1 = *(const s16x8*)(WpG + (p * 64 + col) * 64 + ph1 * 8);
            ac0[ct] = __builtin_amdgcn_mfma_f32_16x16x32_bf16(a_h1, b0, ac0[ct], 0, 0, 0);
            ac1[ct] = __builtin_amdgcn_mfma_f32_16x16x32_bf16(a_m, b1, ac1[ct], 0, 0, 0);
        }
        #pragma unroll
        for (int hh = 0; hh < 2; hh++)
            #pragma unroll
            for (int r = 0; r < 4; r++) {
                float z0l = ac0[hh][r]     + bG[g0 * 64 + hh * 16 + j];
                float z0r = ac0[2 + hh][r] + bG[g0 * 64 + 32 + hh * 16 + j];
                float z1l = ac1[hh][r]     + bG[g1 * 64 + hh * 16 + j];
                float z1r = ac1[2 + hh][r] + bG[g1 * 64 + 32 + hh * 16 + j];
                SX[p][lane][hh * 4 + r] = z0l * sig_acc(z0r) + z1l * sig_acc(z1r);
            }
    }
    __syncthreads();

    {
        int pl = ((erow >> 2) << 4) | ej;
        int ridx = erow & 3;
        #pragma unroll
        for (int hh = 0; hh < 2; hh++) {
            float s0 = SX[0][pl][hh * 4 + ridx];
            float s1 = SX[1][pl][hh * 4 + ridx];
            float s2 = SX[2][pl][hh * 4 + ridx];
            float i2 = sig_acc(s0);
            float gg = sig_acc(s1);
            float o2 = sig_acc(s2);
            float mn = i2 * mv[hh] + (1.0f - i2) * gg;
            size_t gidx = ((size_t)(b * NN + n0 + erow)) * FF + ej + hh * 16;
            mnew[gidx] = mn;
            hnew[gidx] = mn * o2;
        }
    }
}

extern "C" void kernel_launch(void* const* d_in, const int* in_sizes, int n_in,
                              void* d_out, int out_size, void* d_ws, size_t ws_size,
                              hipStream_t stream) {
    (void)in_sizes; (void)n_in; (void)out_size;
    const float* x   = (const float*)d_in[0];
    const float* h   = (const float*)d_in[1];
    const float* c   = (const float*)d_in[2];
    const float* m   = (const float*)d_in[3];
    const float* adj = (const float*)d_in[4];
    const float* W   = (const float*)d_in[5];
    const float* bb  = (const float*)d_in[6];
    float* out = (float*)d_out;

    char* ws = (char*)d_ws;
    // tier A (ws >= 40MB): bf16 adj copy + global_load_lds GEMM staging;
    // tier B: fp32 reg-staging GEMM straight from adj.
    int haveAdjb = ws_size >= (size_t)(40u << 20);
    uint16_t* adjb = (uint16_t*)ws;                              // 32 MB (tier A)
    size_t pOff = haveAdjb ? (size_t)(32u << 20) : 0;
    uint16_t* P    = (uint16_t*)(ws + pOff);                     // 2 MB phase-1 B (x,h)
    uint16_t* P2   = (uint16_t*)(ws + pOff + (2u << 20));        // 2 MB phase-2 B (h1,m)
    uint16_t* Cbuf = (uint16_t*)(ws + pOff + (4u << 20));        // 2 MB GEMM out
    uint16_t* Wp   = (uint16_t*)(ws + pOff + (6u << 20));        // 112 KB packed W

    if (ws_size < (8u << 20)) return;   // harness ws is ~268MB; safety only

    const void* Agemm = haveAdjb ? (const void*)adjb : (const void*)adj;
    int isf32A = haveAdjb ? 0 : 1;
    int cvtN = haveAdjb ? 8192 : 0;

    // ONE prep launch: adj->bf16, W pack, x/h -> P, m -> P2 (all input-only)
    prep_kernel<<<cvtN + 112 + 768, 256, 0, stream>>>(adj, adjb, cvtN, W, Wp, x, h, m, P, P2);

    // phase 1: full-K GEMM1 -> Cbuf bf16 (ax rows 0..127, ah 128..255)
    gemm_kernel<<<dim3(2, 128), 256, 0, stream>>>(Agemm, P, Cbuf, isf32A);
    // fuse1: Cbuf + dense(MFMA) + GLU + LSTM; c_new + h1 -> P2 rows 0..127
    fuse1_kernel<<<1024, 256, 0, stream>>>(Cbuf, Wp, bb, c, out + BNF, P2);
    // phase 2: full-K GEMM2 -> Cbuf (ah1 rows 0..127, am 128..255)
    gemm_kernel<<<dim3(2, 128), 256, 0, stream>>>(Agemm, P2, Cbuf, isf32A);
    fuse2_kernel<<<1024, 256, 0, stream>>>(Cbuf, Wp, bb, m, out, out + 2 * BNF);
}

// Round 9
// 201.296 us; speedup vs baseline: 1.2164x; 1.2164x over previous
//
#include <hip/hip_runtime.h>
#include <stdint.h>

typedef __attribute__((ext_vector_type(4))) float f32x4;
typedef __attribute__((ext_vector_type(8))) short s16x8;

#define BB 4
#define NN 4096
#define FF 32
#define BNF (BB*NN*FF)   // 524288

typedef __attribute__((address_space(3))) void       as3_void;
typedef const __attribute__((address_space(1))) void as1_cvoid;

// ---------- bf16 helpers ----------
static __device__ __forceinline__ float bf2f(uint16_t u) {
    union { uint32_t i; float f; } v; v.i = ((uint32_t)u) << 16; return v.f;
}
static __device__ __forceinline__ uint16_t f2bf(float f) {
    union { float f; uint32_t i; } v; v.f = f;
    uint32_t r = v.i + 0x7FFFu + ((v.i >> 16) & 1u);
    return (uint16_t)(r >> 16);
}
static __device__ __forceinline__ float sig_acc(float x) { return 1.0f / (1.0f + expf(-x)); }

// ======================================================================
// prep: ONE launch for all input-only work.  (unchanged)
// ======================================================================
__global__ __launch_bounds__(256) void prep_kernel(
    const float* __restrict__ adj, uint16_t* __restrict__ adjb, int cvtN,
    const float* __restrict__ Wf, uint16_t* __restrict__ Wp,
    const float* __restrict__ x, const float* __restrict__ h,
    const float* __restrict__ m,
    uint16_t* __restrict__ P, uint16_t* __restrict__ P2)
{
    int bid = blockIdx.x;
    int t = threadIdx.x;

    if (bid < cvtN) {
        size_t i = ((size_t)bid * 256 + t) * 8;
        float4 v0 = *(const float4*)(adj + i);
        float4 v1 = *(const float4*)(adj + i + 4);
        union { uint4 u; uint16_t e[8]; } o;
        o.e[0] = f2bf(v0.x); o.e[1] = f2bf(v0.y); o.e[2] = f2bf(v0.z); o.e[3] = f2bf(v0.w);
        o.e[4] = f2bf(v1.x); o.e[5] = f2bf(v1.y); o.e[6] = f2bf(v1.z); o.e[7] = f2bf(v1.w);
        *(uint4*)(adjb + i) = o.u;
        return;
    }
    bid -= cvtN;

    if (bid < 112) {
        // W: fp32 [14][32][64] -> bf16 Wp[gp][col][slot^swz][k&7]
        // B-frag (16x16x32): lane l holds B[k=(l>>4)*8+e][col=l&15].
        int idx = bid * 256 + t;                    // 14*32*64 = 28672
        int g   = idx >> 11;
        int k   = (idx >> 6) & 31;
        int col = idx & 63;
        uint16_t v = f2bf(Wf[idx]);                 // Wf[g][k][col]
        int gp = g >> 1;
        int sl = ((g & 1) << 2) | (k >> 3);
        int ph = sl ^ (col & 7);
        Wp[((gp * 64 + col) * 64) + ph * 8 + (k & 7)] = v;
        return;
    }
    bid -= 112;

    // pack: state [B][N][F] fp32 -> dst[rowbase + b*32 + f][n] bf16
    const float* src; uint16_t* dst; int rowbase, b, n0;
    if (bid < 512) {
        int tensor = bid >> 8;
        src = tensor ? h : x; dst = P; rowbase = tensor * 128;
        b = (bid >> 6) & 3; n0 = (bid & 63) * 64;
    } else {
        int q = bid - 512;
        src = m; dst = P2; rowbase = 128;
        b = q >> 6; n0 = (q & 63) * 64;
    }
    __shared__ uint16_t tl[32][65];
    {
        int i = t >> 2, ch = t & 3;       // node i (0..63), f-chunk ch (8 floats)
        size_t idx = ((size_t)(b * NN + n0 + i)) * FF + ch * 8;
        float4 v0 = *(const float4*)(src + idx);
        float4 v1 = *(const float4*)(src + idx + 4);
        uint16_t e[8] = { f2bf(v0.x), f2bf(v0.y), f2bf(v0.z), f2bf(v0.w),
                          f2bf(v1.x), f2bf(v1.y), f2bf(v1.z), f2bf(v1.w) };
        #pragma unroll
        for (int k = 0; k < 8; k++) tl[ch * 8 + k][i] = e[k];
    }
    __syncthreads();
    {
        int f = t >> 3, ch = t & 7;
        union { uint4 u; uint16_t e[8]; } v;
        #pragma unroll
        for (int k = 0; k < 8; k++) v.e[k] = tl[f][ch * 8 + k];
        size_t row = (size_t)(rowbase + b * 32 + f);
        *(uint4*)(dst + row * NN + n0 + ch * 8) = v.u;
    }
}

// ---------- GEMM: Cb[c][m] = bf16( sum_k adj[m][k] * Bt[c][k] ) ----------
// Full-K, direct bf16 output.  Grid (nt=4, mt=256) = 1024 blocks = 4/CU
// (16 waves/CU: TLP hides the per-step load latency that capped R8 at 1 blk/CU
//  -> 60us).  M-tile 16, C-tile 64, two BK=32 sub-tiles per iteration
// (64 iters, 2 MFMA/wave/iter).  A-tile re-reads across the 4 nt-blocks are
// L3-served (R8: 64MB logical -> 36.9MB FETCH).
// Staging/ds_read swizzle formulas byte-identical to the validated 64B-row
// XOR scheme; sub-tile q adds q*32 to the k offset.
__global__ __launch_bounds__(256) void gemm_kernel(
    const void* __restrict__ Av,      // adj: bf16 (isf32A=0) or fp32 (isf32A=1)
    const uint16_t* __restrict__ Bt,  // [256][4096] bf16
    uint16_t* __restrict__ Cb,        // [256][4096] bf16
    int isf32A)
{
    int nt = blockIdx.x, mt = blockIdx.y;
    int m0 = mt * 16, c0 = nt * 64;
    __shared__ __align__(16) uint16_t aL[2][16 * 32];   // 2 x 1 KB
    __shared__ __align__(16) uint16_t bL[2][64 * 32];   // 2 x 4 KB
    int t = threadIdx.x;
    int lane = t & 63, w = t >> 6;
    int lm = lane & 15, lk = lane >> 4;

    const uint16_t* A16 = (const uint16_t*)Av;
    const float*    Af  = (const float*)Av;

    f32x4 acc = {};

    for (int kk = 0; kk < 4096; kk += 64) {
        if (!isf32A) {
            if (t < 128) {                               // A: 2 bufs x 64 x 16B
                int q = t >> 6, pos = (t & 63) * 16;
                int row = pos >> 6;
                int slot = ((pos >> 4) & 3) ^ ((row >> 1) & 3);
                size_t aidx = (size_t)(m0 + row) * 4096 + kk + q * 32 + slot * 8;
                __builtin_amdgcn_global_load_lds((as1_cvoid*)(A16 + aidx),
                    (as3_void*)((char*)aL[q] + pos), 16, 0, 0);
            }
            #pragma unroll
            for (int q = 0; q < 2; q++) {                // B: 2 bufs x 256 x 16B
                int pos = t * 16;
                int row = pos >> 6;
                int slot = ((pos >> 4) & 3) ^ ((row >> 1) & 3);
                size_t bidx = (size_t)(c0 + row) * 4096 + kk + q * 32 + slot * 8;
                __builtin_amdgcn_global_load_lds((as1_cvoid*)(Bt + bidx),
                    (as3_void*)((char*)bL[q] + pos), 16, 0, 0);
            }
        } else {
            union { uint4 u; uint16_t e[8]; } sa, sb[2];
            int aq = t >> 6, apos = (t & 63) * 16;
            if (t < 128) {
                int row = apos >> 6;
                int slot = ((apos >> 4) & 3) ^ ((row >> 1) & 3);
                size_t aidx = (size_t)(m0 + row) * 4096 + kk + aq * 32 + slot * 8;
                union { uint4 u[2]; float f[8]; } va;
                va.u[0] = *(const uint4*)(Af + aidx);
                va.u[1] = *(const uint4*)(Af + aidx + 4);
                #pragma unroll
                for (int k = 0; k < 8; k++) sa.e[k] = f2bf(va.f[k]);
            }
            #pragma unroll
            for (int q = 0; q < 2; q++) {
                int pos = t * 16;
                int row = pos >> 6;
                int slot = ((pos >> 4) & 3) ^ ((row >> 1) & 3);
                size_t bidx = (size_t)(c0 + row) * 4096 + kk + q * 32 + slot * 8;
                sb[q].u = *(const uint4*)(Bt + bidx);
            }
            if (t < 128) *(uint4*)((char*)aL[aq] + apos) = sa.u;
            #pragma unroll
            for (int q = 0; q < 2; q++)
                *(uint4*)((char*)bL[q] + t * 16) = sb[q].u;
        }
        __syncthreads();
        s16x8 af0, af1, bf0, bf1;
        {
            int r = lm, sw = (lk ^ ((r >> 1) & 3)) * 8;
            af0 = *(const s16x8*)(aL[0] + r * 32 + sw);
            af1 = *(const s16x8*)(aL[1] + r * 32 + sw);
        }
        {
            int r = w * 16 + lm, sw = (lk ^ ((r >> 1) & 3)) * 8;
            bf0 = *(const s16x8*)(bL[0] + r * 32 + sw);
            bf1 = *(const s16x8*)(bL[1] + r * 32 + sw);
        }
        acc = __builtin_amdgcn_mfma_f32_16x16x32_bf16(af0, bf0, acc, 0, 0, 0);
        acc = __builtin_amdgcn_mfma_f32_16x16x32_bf16(af1, bf1, acc, 0, 0, 0);
        __syncthreads();
    }

    // C/D layout: col=lane&15 (c dim), row=(lane>>4)*4+reg (m dim)
    {
        int c = c0 + w * 16 + lm;
        int mr = m0 + lk * 4;
        union { uint2 u; uint16_t e[4]; } v;
        #pragma unroll
        for (int r = 0; r < 4; r++) v.e[r] = f2bf(acc[r]);
        *(uint2*)(Cb + (size_t)c * 4096 + mr) = v.u;
    }
}

// ======================================================================
// fuse1: 1024 blocks x 256 threads (4 waves); block = (batch b, 16 nodes).
// Phase 1: cooperative load of Cbuf (bf16).
// Phase 2: all waves build identical A-frags; wave w computes gate-pair w
//          (B-frags direct from global Wp, L2-broadcast) -> GLU -> SX.
// Phase 3: all 256 threads do the LSTM update from SX; pack h1 -> P2.
// ======================================================================
__global__ __launch_bounds__(256) void fuse1_kernel(
    const uint16_t* __restrict__ Cbi, // [256][4096] bf16
    const uint16_t* __restrict__ Wp,  // packed W (prep)
    const float* __restrict__ bf_,
    const float* __restrict__ cf,
    float* __restrict__ cnew, uint16_t* __restrict__ S2t)
{
    __shared__ float    AL[64 * 17];   // [c'][node 0..15], pitch 17
    __shared__ float    SX[4][64][9];  // per-gate-pair GLU outputs (pad 9)
    __shared__ uint16_t H1[32 * 18];   // [f][node]

    int t = threadIdx.x;
    int bid = blockIdx.x;              // 1024
    int b = bid >> 8, n0 = (bid & 255) * 16;
    int lane = t & 63, w = t >> 6;
    int j = lane & 15, kg = lane >> 4;
    int ej = t & 15, erow = (t >> 4) & 15;   // element coords for phase 3

    // c prefetch for phase 3 (in flight under phase 1)
    float cv[2];
    #pragma unroll
    for (int hh = 0; hh < 2; hh++)
        cv[hh] = cf[((size_t)(b * NN + n0 + erow)) * FF + ej + hh * 16];

    // phase 1: load Cbuf. thread t -> c'-row r = t>>2, chunk ch = t&3.
    {
        int r = t >> 2, ch = t & 3;
        int crow = (r < 32) ? (b * 32 + r) : (128 + b * 32 + (r - 32));
        const uint16_t* cp = Cbi + (size_t)crow * 4096 + n0 + ch * 4;
        uint2 v = *(const uint2*)cp;
        const uint16_t* pe = (const uint16_t*)&v;
        #pragma unroll
        for (int e = 0; e < 4; e++) AL[r * 17 + ch * 4 + e] = bf2f(pe[e]);
    }
    __syncthreads();

    // phase 2: A frags (identical in every wave); wave w = gate-pair w
    s16x8 a_ax, a_ah;
    #pragma unroll
    for (int e = 0; e < 8; e++) {
        int k = kg * 8 + e;
        a_ax[e] = (short)f2bf(AL[k * 17 + j]);
        a_ah[e] = (short)f2bf(AL[(32 + k) * 17 + j]);
    }
    {
        int p = w;                                // gate-pair: even=ax, odd=ah
        int g0 = p * 2, g1 = p * 2 + 1;
        f32x4 ac0[4] = {}, ac1[4] = {};
        #pragma unroll
        for (int ct = 0; ct < 4; ct++) {
            int col = ct * 16 + j;
            int ph0 = (kg)     ^ (col & 7);
            int ph1 = (4 + kg) ^ (col & 7);
            s16x8 b0 = *(const s16x8*)(Wp + (p * 64 + col) * 64 + ph0 * 8);
            s16x8 b1 = *(const s16x8*)(Wp + (p * 64 + col) * 64 + ph1 * 8);
            ac0[ct] = __builtin_amdgcn_mfma_f32_16x16x32_bf16(a_ax, b0, ac0[ct], 0, 0, 0);
            ac1[ct] = __builtin_amdgcn_mfma_f32_16x16x32_bf16(a_ah, b1, ac1[ct], 0, 0, 0);
        }
        #pragma unroll
        for (int hh = 0; hh < 2; hh++)
            #pragma unroll
            for (int r = 0; r < 4; r++) {
                float z0l = ac0[hh][r]     + bf_[g0 * 64 + hh * 16 + j];
                float z0r = ac0[2 + hh][r] + bf_[g0 * 64 + 32 + hh * 16 + j];
                float z1l = ac1[hh][r]     + bf_[g1 * 64 + hh * 16 + j];
                float z1r = ac1[2 + hh][r] + bf_[g1 * 64 + 32 + hh * 16 + j];
                SX[p][lane][hh * 4 + r] = z0l * sig_acc(z0r) + z1l * sig_acc(z1r);
            }
    }
    __syncthreads();

    // phase 3: LSTM update; thread t handles element (erow, ej), hh=0,1
    {
        int pl = ((erow >> 2) << 4) | ej;         // producer lane
        int ridx = erow & 3;
        #pragma unroll
        for (int hh = 0; hh < 2; hh++) {
            float s0 = SX[0][pl][hh * 4 + ridx];
            float s1 = SX[1][pl][hh * 4 + ridx];
            float s2 = SX[2][pl][hh * 4 + ridx];
            float s3 = SX[3][pl][hh * 4 + ridx];
            float fg = sig_acc(s0), ig = sig_acc(s1);
            float cc = tanhf(s2),   og = sig_acc(s3);
            float cn = fg * cv[hh] + ig * cc;
            size_t gidx = ((size_t)(b * NN + n0 + erow)) * FF + ej + hh * 16;
            cnew[gidx] = cn;
            H1[(ej + hh * 16) * 18 + erow] = f2bf(og * tanhf(cn));
        }
    }
    __syncthreads();
    if (t < 64) {   // pack h1 -> P2 rows b*32+f (GEMM2 B operand, rows 0..127)
        int f = t >> 1, half = t & 1;
        union { uint4 u; uint16_t e[8]; } v;
        #pragma unroll
        for (int k = 0; k < 8; k++) v.e[k] = H1[f * 18 + half * 8 + k];
        *(uint4*)(S2t + ((size_t)(b * 32 + f)) * NN + n0 + half * 8) = v.u;
    }
}

// ======================================================================
// fuse2: same structure, 3 gate-pairs (waves 0..2; wave 3 idles in phase 2).
// ======================================================================
__global__ __launch_bounds__(256) void fuse2_kernel(
    const uint16_t* __restrict__ Cbi,
    const uint16_t* __restrict__ Wp,
    const float* __restrict__ bf_,
    const float* __restrict__ mf,
    float* __restrict__ hnew, float* __restrict__ mnew)
{
    __shared__ float AL[64 * 17];
    __shared__ float SX[3][64][9];

    int t = threadIdx.x;
    int bid = blockIdx.x;
    int b = bid >> 8, n0 = (bid & 255) * 16;
    int lane = t & 63, w = t >> 6;
    int j = lane & 15, kg = lane >> 4;
    int ej = t & 15, erow = (t >> 4) & 15;

    float mv[2];
    #pragma unroll
    for (int hh = 0; hh < 2; hh++)
        mv[hh] = mf[((size_t)(b * NN + n0 + erow)) * FF + ej + hh * 16];

    {
        int r = t >> 2, ch = t & 3;
        int crow = (r < 32) ? (b * 32 + r) : (128 + b * 32 + (r - 32));
        const uint16_t* cp = Cbi + (size_t)crow * 4096 + n0 + ch * 4;
        uint2 v = *(const uint2*)cp;
        const uint16_t* pe = (const uint16_t*)&v;
        #pragma unroll
        for (int e = 0; e < 4; e++) AL[r * 17 + ch * 4 + e] = bf2f(pe[e]);
    }
    __syncthreads();

    if (w < 3) {
        s16x8 a_h1, a_m;
        #pragma unroll
        for (int e = 0; e < 8; e++) {
            int k = kg * 8 + e;
            a_h1[e] = (short)f2bf(AL[k * 17 + j]);
            a_m[e]  = (short)f2bf(AL[(32 + k) * 17 + j]);
        }
        const uint16_t* WpG = Wp + 4 * 64 * 64;   // gate-pairs 4..6 (gates 8..13)
        const float*    bG  = bf_ + 512;
        int p = w;
        int g0 = p * 2, g1 = p * 2 + 1;           // even: ah1, odd: am
        f32x4 ac0[4] = {}, ac1[4] = {};
        #pragma unroll
        for (int ct = 0; ct < 4; ct++) {
            int col = ct * 16 + j;
            int ph0 = (kg)     ^ (col & 7);
            int ph1 = (4 + kg) ^ (col & 7);
            s16x8 b0 = *(const s16x8*)(WpG + (p * 64 + col) * 64 + ph0 * 8);
            s16x8 b1 = *(const s16x8*)(WpG + (p * 64 + col) * 64 + ph1 * 8);
            ac0[ct] = __builtin_amdgcn_mfma_f32_16x16x32_bf16(a_h1, b0, ac0[ct], 0, 0, 0);
            ac1[ct] = __builtin_amdgcn_mfma_f32_16x16x32_bf16(a_m, b1, ac1[ct], 0, 0, 0);
        }
        #pragma unroll
        for (int hh = 0; hh < 2; hh++)
            #pragma unroll
            for (int r = 0; r < 4; r++) {
                float z0l = ac0[hh][r]     + bG[g0 * 64 + hh * 16 + j];
                float z0r = ac0[2 + hh][r] + bG[g0 * 64 + 32 + hh * 16 + j];
                float z1l = ac1[hh][r]     + bG[g1 * 64 + hh * 16 + j];
                float z1r = ac1[2 + hh][r] + bG[g1 * 64 + 32 + hh * 16 + j];
                SX[p][lane][hh * 4 + r] = z0l * sig_acc(z0r) + z1l * sig_acc(z1r);
            }
    }
    __syncthreads();

    {
        int pl = ((erow >> 2) << 4) | ej;
        int ridx = erow & 3;
        #pragma unroll
        for (int hh = 0; hh < 2; hh++) {
            float s0 = SX[0][pl][hh * 4 + ridx];
            float s1 = SX[1][pl][hh * 4 + ridx];
            float s2 = SX[2][pl][hh * 4 + ridx];
            float i2 = sig_acc(s0);
            float gg = sig_acc(s1);
            float o2 = sig_acc(s2);
            float mn = i2 * mv[hh] + (1.0f - i2) * gg;
            size_t gidx = ((size_t)(b * NN + n0 + erow)) * FF + ej + hh * 16;
            mnew[gidx] = mn;
            hnew[gidx] = mn * o2;
        }
    }
}

extern "C" void kernel_launch(void* const* d_in, const int* in_sizes, int n_in,
                              void* d_out, int out_size, void* d_ws, size_t ws_size,
                              hipStream_t stream) {
    (void)in_sizes; (void)n_in; (void)out_size;
    const float* x   = (const float*)d_in[0];
    const float* h   = (const float*)d_in[1];
    const float* c   = (const float*)d_in[2];
    const float* m   = (const float*)d_in[3];
    const float* adj = (const float*)d_in[4];
    const float* W   = (const float*)d_in[5];
    const float* bb  = (const float*)d_in[6];
    float* out = (float*)d_out;

    char* ws = (char*)d_ws;
    // tier A (ws >= 40MB): bf16 adj copy + global_load_lds GEMM staging;
    // tier B: fp32 reg-staging GEMM straight from adj.
    int haveAdjb = ws_size >= (size_t)(40u << 20);
    uint16_t* adjb = (uint16_t*)ws;                              // 32 MB (tier A)
    size_t pOff = haveAdjb ? (size_t)(32u << 20) : 0;
    uint16_t* P    = (uint16_t*)(ws + pOff);                     // 2 MB phase-1 B (x,h)
    uint16_t* P2   = (uint16_t*)(ws + pOff + (2u << 20));        // 2 MB phase-2 B (h1,m)
    uint16_t* Cbuf = (uint16_t*)(ws + pOff + (4u << 20));        // 2 MB GEMM out
    uint16_t* Wp   = (uint16_t*)(ws + pOff + (6u << 20));        // 112 KB packed W

    if (ws_size < (8u << 20)) return;   // harness ws is ~268MB; safety only

    const void* Agemm = haveAdjb ? (const void*)adjb : (const void*)adj;
    int isf32A = haveAdjb ? 0 : 1;
    int cvtN = haveAdjb ? 8192 : 0;

    // ONE prep launch: adj->bf16, W pack, x/h -> P, m -> P2 (all input-only)
    prep_kernel<<<cvtN + 112 + 768, 256, 0, stream>>>(adj, adjb, cvtN, W, Wp, x, h, m, P, P2);

    // phase 1: full-K GEMM1 -> Cbuf bf16 (ax rows 0..127, ah 128..255)
    gemm_kernel<<<dim3(4, 256), 256, 0, stream>>>(Agemm, P, Cbuf, isf32A);
    // fuse1: Cbuf + dense(MFMA) + GLU + LSTM; c_new + h1 -> P2 rows 0..127
    fuse1_kernel<<<1024, 256, 0, stream>>>(Cbuf, Wp, bb, c, out + BNF, P2);
    // phase 2: full-K GEMM2 -> Cbuf (ah1 rows 0..127, am 128..255)
    gemm_kernel<<<dim3(4, 256), 256, 0, stream>>>(Agemm, P2, Cbuf, isf32A);
    fuse2_kernel<<<1024, 256, 0, stream>>>(Cbuf, Wp, bb, m, out, out + 2 * BNF);
}

// Round 10
// 198.940 us; speedup vs baseline: 1.2308x; 1.0118x over previous
//
#include <hip/hip_runtime.h>
#include <stdint.h>

typedef __attribute__((ext_vector_type(4))) float f32x4;
typedef __attribute__((ext_vector_type(8))) short s16x8;

#define BB 4
#define NN 4096
#define FF 32
#define BNF (BB*NN*FF)   // 524288

typedef __attribute__((address_space(3))) void       as3_void;
typedef const __attribute__((address_space(1))) void as1_cvoid;

// ---------- bf16 helpers ----------
static __device__ __forceinline__ float bf2f(uint16_t u) {
    union { uint32_t i; float f; } v; v.i = ((uint32_t)u) << 16; return v.f;
}
static __device__ __forceinline__ uint16_t f2bf(float f) {
    union { float f; uint32_t i; } v; v.f = f;
    uint32_t r = v.i + 0x7FFFu + ((v.i >> 16) & 1u);
    return (uint16_t)(r >> 16);
}
static __device__ __forceinline__ float sig_acc(float x) { return 1.0f / (1.0f + expf(-x)); }

// ======================================================================
// prep: ONE launch for all input-only work.  (unchanged)
// ======================================================================
__global__ __launch_bounds__(256) void prep_kernel(
    const float* __restrict__ adj, uint16_t* __restrict__ adjb, int cvtN,
    const float* __restrict__ Wf, uint16_t* __restrict__ Wp,
    const float* __restrict__ x, const float* __restrict__ h,
    const float* __restrict__ m,
    uint16_t* __restrict__ P, uint16_t* __restrict__ P2)
{
    int bid = blockIdx.x;
    int t = threadIdx.x;

    if (bid < cvtN) {
        size_t i = ((size_t)bid * 256 + t) * 8;
        float4 v0 = *(const float4*)(adj + i);
        float4 v1 = *(const float4*)(adj + i + 4);
        union { uint4 u; uint16_t e[8]; } o;
        o.e[0] = f2bf(v0.x); o.e[1] = f2bf(v0.y); o.e[2] = f2bf(v0.z); o.e[3] = f2bf(v0.w);
        o.e[4] = f2bf(v1.x); o.e[5] = f2bf(v1.y); o.e[6] = f2bf(v1.z); o.e[7] = f2bf(v1.w);
        *(uint4*)(adjb + i) = o.u;
        return;
    }
    bid -= cvtN;

    if (bid < 112) {
        // W: fp32 [14][32][64] -> bf16 Wp[gp][col][slot^swz][k&7]
        // B-frag (16x16x32): lane l holds B[k=(l>>4)*8+e][col=l&15].
        int idx = bid * 256 + t;                    // 14*32*64 = 28672
        int g   = idx >> 11;
        int k   = (idx >> 6) & 31;
        int col = idx & 63;
        uint16_t v = f2bf(Wf[idx]);                 // Wf[g][k][col]
        int gp = g >> 1;
        int sl = ((g & 1) << 2) | (k >> 3);
        int ph = sl ^ (col & 7);
        Wp[((gp * 64 + col) * 64) + ph * 8 + (k & 7)] = v;
        return;
    }
    bid -= 112;

    // pack: state [B][N][F] fp32 -> dst[rowbase + b*32 + f][n] bf16
    const float* src; uint16_t* dst; int rowbase, b, n0;
    if (bid < 512) {
        int tensor = bid >> 8;
        src = tensor ? h : x; dst = P; rowbase = tensor * 128;
        b = (bid >> 6) & 3; n0 = (bid & 63) * 64;
    } else {
        int q = bid - 512;
        src = m; dst = P2; rowbase = 128;
        b = q >> 6; n0 = (q & 63) * 64;
    }
    __shared__ uint16_t tl[32][65];
    {
        int i = t >> 2, ch = t & 3;       // node i (0..63), f-chunk ch (8 floats)
        size_t idx = ((size_t)(b * NN + n0 + i)) * FF + ch * 8;
        float4 v0 = *(const float4*)(src + idx);
        float4 v1 = *(const float4*)(src + idx + 4);
        uint16_t e[8] = { f2bf(v0.x), f2bf(v0.y), f2bf(v0.z), f2bf(v0.w),
                          f2bf(v1.x), f2bf(v1.y), f2bf(v1.z), f2bf(v1.w) };
        #pragma unroll
        for (int k = 0; k < 8; k++) tl[ch * 8 + k][i] = e[k];
    }
    __syncthreads();
    {
        int f = t >> 3, ch = t & 7;
        union { uint4 u; uint16_t e[8]; } v;
        #pragma unroll
        for (int k = 0; k < 8; k++) v.e[k] = tl[f][ch * 8 + k];
        size_t row = (size_t)(rowbase + b * 32 + f);
        *(uint4*)(dst + row * NN + n0 + ch * 8) = v.u;
    }
}

// ---------- GEMM: Cb[c][m] = bf16( sum_k adj[m][k] * Bt[c][k] ) ----------
// Full-K, direct bf16 output.  Grid (nt=4, mt=256) = 1024 blocks = 4/CU.
// BK=128 per barrier pair (4 x BK32 sub-buffers) -> 32 iterations: halves the
// vmcnt(0)-drain/barrier count that made the 64-iter R9 loop latency-bound
// (R8 1blk/CU = 60us; R9 4blk/CU 64 iters ~38us; per-block serial chain is
// the wall time since all blocks are co-resident).
// LDS 20 KB -> still 4 blocks/CU (80 KB < 160 KB).
// Staging/ds_read swizzle byte-identical to the validated 64B-row XOR scheme;
// sub-tile q adds q*32 to the k offset.
__global__ __launch_bounds__(256) void gemm_kernel(
    const void* __restrict__ Av,      // adj: bf16 (isf32A=0) or fp32 (isf32A=1)
    const uint16_t* __restrict__ Bt,  // [256][4096] bf16
    uint16_t* __restrict__ Cb,        // [256][4096] bf16
    int isf32A)
{
    int nt = blockIdx.x, mt = blockIdx.y;
    int m0 = mt * 16, c0 = nt * 64;
    __shared__ __align__(16) uint16_t aL[4][16 * 32];   // 4 x 1 KB
    __shared__ __align__(16) uint16_t bL[4][64 * 32];   // 4 x 4 KB
    int t = threadIdx.x;
    int lane = t & 63, w = t >> 6;
    int lm = lane & 15, lk = lane >> 4;

    const uint16_t* A16 = (const uint16_t*)Av;
    const float*    Af  = (const float*)Av;

    f32x4 acc = {};

    for (int kk = 0; kk < 4096; kk += 128) {
        if (!isf32A) {
            {                                            // A: 4 bufs x 64 x 16B
                int q = t >> 6, pos = (t & 63) * 16;
                int row = pos >> 6;
                int slot = ((pos >> 4) & 3) ^ ((row >> 1) & 3);
                size_t aidx = (size_t)(m0 + row) * 4096 + kk + q * 32 + slot * 8;
                __builtin_amdgcn_global_load_lds((as1_cvoid*)(A16 + aidx),
                    (as3_void*)((char*)aL[q] + pos), 16, 0, 0);
            }
            #pragma unroll
            for (int q = 0; q < 4; q++) {                // B: 4 bufs x 256 x 16B
                int pos = t * 16;
                int row = pos >> 6;
                int slot = ((pos >> 4) & 3) ^ ((row >> 1) & 3);
                size_t bidx = (size_t)(c0 + row) * 4096 + kk + q * 32 + slot * 8;
                __builtin_amdgcn_global_load_lds((as1_cvoid*)(Bt + bidx),
                    (as3_void*)((char*)bL[q] + pos), 16, 0, 0);
            }
        } else {
            union { uint4 u; uint16_t e[8]; } sa, sb[4];
            int aq = t >> 6, apos = (t & 63) * 16;
            {
                int row = apos >> 6;
                int slot = ((apos >> 4) & 3) ^ ((row >> 1) & 3);
                size_t aidx = (size_t)(m0 + row) * 4096 + kk + aq * 32 + slot * 8;
                union { uint4 u[2]; float f[8]; } va;
                va.u[0] = *(const uint4*)(Af + aidx);
                va.u[1] = *(const uint4*)(Af + aidx + 4);
                #pragma unroll
                for (int k = 0; k < 8; k++) sa.e[k] = f2bf(va.f[k]);
            }
            #pragma unroll
            for (int q = 0; q < 4; q++) {
                int pos = t * 16;
                int row = pos >> 6;
                int slot = ((pos >> 4) & 3) ^ ((row >> 1) & 3);
                size_t bidx = (size_t)(c0 + row) * 4096 + kk + q * 32 + slot * 8;
                sb[q].u = *(const uint4*)(Bt + bidx);
            }
            *(uint4*)((char*)aL[aq] + apos) = sa.u;
            #pragma unroll
            for (int q = 0; q < 4; q++)
                *(uint4*)((char*)bL[q] + t * 16) = sb[q].u;
        }
        __syncthreads();
        {
            int rA = lm,          swA = (lk ^ ((rA >> 1) & 3)) * 8;
            int rB = w * 16 + lm, swB = (lk ^ ((rB >> 1) & 3)) * 8;
            #pragma unroll
            for (int q = 0; q < 4; q++) {
                s16x8 af = *(const s16x8*)(aL[q] + rA * 32 + swA);
                s16x8 bf = *(const s16x8*)(bL[q] + rB * 32 + swB);
                acc = __builtin_amdgcn_mfma_f32_16x16x32_bf16(af, bf, acc, 0, 0, 0);
            }
        }
        __syncthreads();
    }

    // C/D layout: col=lane&15 (c dim), row=(lane>>4)*4+reg (m dim)
    {
        int c = c0 + w * 16 + lm;
        int mr = m0 + lk * 4;
        union { uint2 u; uint16_t e[4]; } v;
        #pragma unroll
        for (int r = 0; r < 4; r++) v.e[r] = f2bf(acc[r]);
        *(uint2*)(Cb + (size_t)c * 4096 + mr) = v.u;
    }
}

// ======================================================================
// fuse1: 1024 blocks x 256 threads (4 waves); block = (batch b, 16 nodes).
// Phase 1: cooperative load of Cbuf (bf16).
// Phase 2: all waves build identical A-frags; wave w computes gate-pair w
//          (B-frags direct from global Wp, L2-broadcast) -> GLU -> SX.
// Phase 3: all 256 threads do the LSTM update from SX; pack h1 -> P2.
// ======================================================================
__global__ __launch_bounds__(256) void fuse1_kernel(
    const uint16_t* __restrict__ Cbi, // [256][4096] bf16
    const uint16_t* __restrict__ Wp,  // packed W (prep)
    const float* __restrict__ bf_,
    const float* __restrict__ cf,
    float* __restrict__ cnew, uint16_t* __restrict__ S2t)
{
    __shared__ float    AL[64 * 17];   // [c'][node 0..15], pitch 17
    __shared__ float    SX[4][64][9];  // per-gate-pair GLU outputs (pad 9)
    __shared__ uint16_t H1[32 * 18];   // [f][node]

    int t = threadIdx.x;
    int bid = blockIdx.x;              // 1024
    int b = bid >> 8, n0 = (bid & 255) * 16;
    int lane = t & 63, w = t >> 6;
    int j = lane & 15, kg = lane >> 4;
    int ej = t & 15, erow = (t >> 4) & 15;   // element coords for phase 3

    // c prefetch for phase 3 (in flight under phase 1)
    float cv[2];
    #pragma unroll
    for (int hh = 0; hh < 2; hh++)
        cv[hh] = cf[((size_t)(b * NN + n0 + erow)) * FF + ej + hh * 16];

    // phase 1: load Cbuf. thread t -> c'-row r = t>>2, chunk ch = t&3.
    {
        int r = t >> 2, ch = t & 3;
        int crow = (r < 32) ? (b * 32 + r) : (128 + b * 32 + (r - 32));
        const uint16_t* cp = Cbi + (size_t)crow * 4096 + n0 + ch * 4;
        uint2 v = *(const uint2*)cp;
        const uint16_t* pe = (const uint16_t*)&v;
        #pragma unroll
        for (int e = 0; e < 4; e++) AL[r * 17 + ch * 4 + e] = bf2f(pe[e]);
    }
    __syncthreads();

    // phase 2: A frags (identical in every wave); wave w = gate-pair w
    s16x8 a_ax, a_ah;
    #pragma unroll
    for (int e = 0; e < 8; e++) {
        int k = kg * 8 + e;
        a_ax[e] = (short)f2bf(AL[k * 17 + j]);
        a_ah[e] = (short)f2bf(AL[(32 + k) * 17 + j]);
    }
    {
        int p = w;                                // gate-pair: even=ax, odd=ah
        int g0 = p * 2, g1 = p * 2 + 1;
        f32x4 ac0[4] = {}, ac1[4] = {};
        #pragma unroll
        for (int ct = 0; ct < 4; ct++) {
            int col = ct * 16 + j;
            int ph0 = (kg)     ^ (col & 7);
            int ph1 = (4 + kg) ^ (col & 7);
            s16x8 b0 = *(const s16x8*)(Wp + (p * 64 + col) * 64 + ph0 * 8);
            s16x8 b1 = *(const s16x8*)(Wp + (p * 64 + col) * 64 + ph1 * 8);
            ac0[ct] = __builtin_amdgcn_mfma_f32_16x16x32_bf16(a_ax, b0, ac0[ct], 0, 0, 0);
            ac1[ct] = __builtin_amdgcn_mfma_f32_16x16x32_bf16(a_ah, b1, ac1[ct], 0, 0, 0);
        }
        #pragma unroll
        for (int hh = 0; hh < 2; hh++)
            #pragma unroll
            for (int r = 0; r < 4; r++) {
                float z0l = ac0[hh][r]     + bf_[g0 * 64 + hh * 16 + j];
                float z0r = ac0[2 + hh][r] + bf_[g0 * 64 + 32 + hh * 16 + j];
                float z1l = ac1[hh][r]     + bf_[g1 * 64 + hh * 16 + j];
                float z1r = ac1[2 + hh][r] + bf_[g1 * 64 + 32 + hh * 16 + j];
                SX[p][lane][hh * 4 + r] = z0l * sig_acc(z0r) + z1l * sig_acc(z1r);
            }
    }
    __syncthreads();

    // phase 3: LSTM update; thread t handles element (erow, ej), hh=0,1
    {
        int pl = ((erow >> 2) << 4) | ej;         // producer lane
        int ridx = erow & 3;
        #pragma unroll
        for (int hh = 0; hh < 2; hh++) {
            float s0 = SX[0][pl][hh * 4 + ridx];
            float s1 = SX[1][pl][hh * 4 + ridx];
            float s2 = SX[2][pl][hh * 4 + ridx];
            float s3 = SX[3][pl][hh * 4 + ridx];
            float fg = sig_acc(s0), ig = sig_acc(s1);
            float cc = tanhf(s2),   og = sig_acc(s3);
            float cn = fg * cv[hh] + ig * cc;
            size_t gidx = ((size_t)(b * NN + n0 + erow)) * FF + ej + hh * 16;
            cnew[gidx] = cn;
            H1[(ej + hh * 16) * 18 + erow] = f2bf(og * tanhf(cn));
        }
    }
    __syncthreads();
    if (t < 64) {   // pack h1 -> P2 rows b*32+f (GEMM2 B operand, rows 0..127)
        int f = t >> 1, half = t & 1;
        union { uint4 u; uint16_t e[8]; } v;
        #pragma unroll
        for (int k = 0; k < 8; k++) v.e[k] = H1[f * 18 + half * 8 + k];
        *(uint4*)(S2t + ((size_t)(b * 32 + f)) * NN + n0 + half * 8) = v.u;
    }
}

// ======================================================================
// fuse2: same structure, 3 gate-pairs (waves 0..2; wave 3 idles in phase 2).
// ======================================================================
__global__ __launch_bounds__(256) void fuse2_kernel(
    const uint16_t* __restrict__ Cbi,
    const uint16_t* __restrict__ Wp,
    const float* __restrict__ bf_,
    const float* __restrict__ mf,
    float* __restrict__ hnew, float* __restrict__ mnew)
{
    __shared__ float AL[64 * 17];
    __shared__ float SX[3][64][9];

    int t = threadIdx.x;
    int bid = blockIdx.x;
    int b = bid >> 8, n0 = (bid & 255) * 16;
    int lane = t & 63, w = t >> 6;
    int j = lane & 15, kg = lane >> 4;
    int ej = t & 15, erow = (t >> 4) & 15;

    float mv[2];
    #pragma unroll
    for (int hh = 0; hh < 2; hh++)
        mv[hh] = mf[((size_t)(b * NN + n0 + erow)) * FF + ej + hh * 16];

    {
        int r = t >> 2, ch = t & 3;
        int crow = (r < 32) ? (b * 32 + r) : (128 + b * 32 + (r - 32));
        const uint16_t* cp = Cbi + (size_t)crow * 4096 + n0 + ch * 4;
        uint2 v = *(const uint2*)cp;
        const uint16_t* pe = (const uint16_t*)&v;
        #pragma unroll
        for (int e = 0; e < 4; e++) AL[r * 17 + ch * 4 + e] = bf2f(pe[e]);
    }
    __syncthreads();

    if (w < 3) {
        s16x8 a_h1, a_m;
        #pragma unroll
        for (int e = 0; e < 8; e++) {
            int k = kg * 8 + e;
            a_h1[e] = (short)f2bf(AL[k * 17 + j]);
            a_m[e]  = (short)f2bf(AL[(32 + k) * 17 + j]);
        }
        const uint16_t* WpG = Wp + 4 * 64 * 64;   // gate-pairs 4..6 (gates 8..13)
        const float*    bG  = bf_ + 512;
        int p = w;
        int g0 = p * 2, g1 = p * 2 + 1;           // even: ah1, odd: am
        f32x4 ac0[4] = {}, ac1[4] = {};
        #pragma unroll
        for (int ct = 0; ct < 4; ct++) {
            int col = ct * 16 + j;
            int ph0 = (kg)     ^ (col & 7);
            int ph1 = (4 + kg) ^ (col & 7);
            s16x8 b0 = *(const s16x8*)(WpG + (p * 64 + col) * 64 + ph0 * 8);
            s16x8 b1 = *(const s16x8*)(WpG + (p * 64 + col) * 64 + ph1 * 8);
            ac0[ct] = __builtin_amdgcn_mfma_f32_16x16x32_bf16(a_h1, b0, ac0[ct], 0, 0, 0);
            ac1[ct] = __builtin_amdgcn_mfma_f32_16x16x32_bf16(a_m, b1, ac1[ct], 0, 0, 0);
        }
        #pragma unroll
        for (int hh = 0; hh < 2; hh++)
            #pragma unroll
            for (int r = 0; r < 4; r++) {
                float z0l = ac0[hh][r]     + bG[g0 * 64 + hh * 16 + j];
                float z0r = ac0[2 + hh][r] + bG[g0 * 64 + 32 + hh * 16 + j];
                float z1l = ac1[hh][r]     + bG[g1 * 64 + hh * 16 + j];
                float z1r = ac1[2 + hh][r] + bG[g1 * 64 + 32 + hh * 16 + j];
                SX[p][lane][hh * 4 + r] = z0l * sig_acc(z0r) + z1l * sig_acc(z1r);
            }
    }
    __syncthreads();

    {
        int pl = ((erow >> 2) << 4) | ej;
        int ridx = erow & 3;
        #pragma unroll
        for (int hh = 0; hh < 2; hh++) {
            float s0 = SX[0][pl][hh * 4 + ridx];
            float s1 = SX[1][pl][hh * 4 + ridx];
            float s2 = SX[2][pl][hh * 4 + ridx];
            float i2 = sig_acc(s0);
            float gg = sig_acc(s1);
            float o2 = sig_acc(s2);
            float mn = i2 * mv[hh] + (1.0f - i2) * gg;
            size_t gidx = ((size_t)(b * NN + n0 + erow)) * FF + ej + hh * 16;
            mnew[gidx] = mn;
            hnew[gidx] = mn * o2;
        }
    }
}

extern "C" void kernel_launch(void* const* d_in, const int* in_sizes, int n_in,
                              void* d_out, int out_size, void* d_ws, size_t ws_size,
                              hipStream_t stream) {
    (void)in_sizes; (void)n_in; (void)out_size;
    const float* x   = (const float*)d_in[0];
    const float* h   = (const float*)d_in[1];
    const float* c   = (const float*)d_in[2];
    const float* m   = (const float*)d_in[3];
    const float* adj = (const float*)d_in[4];
    const float* W   = (const float*)d_in[5];
    const float* bb  = (const float*)d_in[6];
    float* out = (float*)d_out;

    char* ws = (char*)d_ws;
    // tier A (ws >= 40MB): bf16 adj copy + global_load_lds GEMM staging;
    // tier B: fp32 reg-staging GEMM straight from adj.
    int haveAdjb = ws_size >= (size_t)(40u << 20);
    uint16_t* adjb = (uint16_t*)ws;                              // 32 MB (tier A)
    size_t pOff = haveAdjb ? (size_t)(32u << 20) : 0;
    uint16_t* P    = (uint16_t*)(ws + pOff);                     // 2 MB phase-1 B (x,h)
    uint16_t* P2   = (uint16_t*)(ws + pOff + (2u << 20));        // 2 MB phase-2 B (h1,m)
    uint16_t* Cbuf = (uint16_t*)(ws + pOff + (4u << 20));        // 2 MB GEMM out
    uint16_t* Wp   = (uint16_t*)(ws + pOff + (6u << 20));        // 112 KB packed W

    if (ws_size < (8u << 20)) return;   // harness ws is ~268MB; safety only

    const void* Agemm = haveAdjb ? (const void*)adjb : (const void*)adj;
    int isf32A = haveAdjb ? 0 : 1;
    int cvtN = haveAdjb ? 8192 : 0;

    // ONE prep launch: adj->bf16, W pack, x/h -> P, m -> P2 (all input-only)
    prep_kernel<<<cvtN + 112 + 768, 256, 0, stream>>>(adj, adjb, cvtN, W, Wp, x, h, m, P, P2);

    // phase 1: full-K GEMM1 -> Cbuf bf16 (ax rows 0..127, ah 128..255)
    gemm_kernel<<<dim3(4, 256), 256, 0, stream>>>(Agemm, P, Cbuf, isf32A);
    // fuse1: Cbuf + dense(MFMA) + GLU + LSTM; c_new + h1 -> P2 rows 0..127
    fuse1_kernel<<<1024, 256, 0, stream>>>(Cbuf, Wp, bb, c, out + BNF, P2);
    // phase 2: full-K GEMM2 -> Cbuf (ah1 rows 0..127, am 128..255)
    gemm_kernel<<<dim3(4, 256), 256, 0, stream>>>(Agemm, P2, Cbuf, isf32A);
    fuse2_kernel<<<1024, 256, 0, stream>>>(Cbuf, Wp, bb, m, out, out + 2 * BNF);
}

// Round 11
// 187.273 us; speedup vs baseline: 1.3074x; 1.0623x over previous
//
#include <hip/hip_runtime.h>
#include <stdint.h>

typedef __attribute__((ext_vector_type(4))) float f32x4;
typedef __attribute__((ext_vector_type(8))) short s16x8;

#define BB 4
#define NN 4096
#define FF 32
#define BNF (BB*NN*FF)   // 524288

typedef __attribute__((address_space(3))) void       as3_void;
typedef const __attribute__((address_space(1))) void as1_cvoid;

// ---------- bf16 helpers ----------
static __device__ __forceinline__ float bf2f(uint16_t u) {
    union { uint32_t i; float f; } v; v.i = ((uint32_t)u) << 16; return v.f;
}
static __device__ __forceinline__ uint16_t f2bf(float f) {
    union { float f; uint32_t i; } v; v.f = f;
    uint32_t r = v.i + 0x7FFFu + ((v.i >> 16) & 1u);
    return (uint16_t)(r >> 16);
}
static __device__ __forceinline__ float sig_acc(float x) { return 1.0f / (1.0f + expf(-x)); }

// ======================================================================
// prep: W pack + state packs (no adj conversion anymore).
//   blocks [0,112):    pack W -> Wp (MFMA B-frag layout, swizzled)
//   blocks [112,880):  pack x,h -> P rows 0..255; m -> P2 rows 128..255
// ======================================================================
__global__ __launch_bounds__(256) void prep_kernel(
    const float* __restrict__ Wf, uint16_t* __restrict__ Wp,
    const float* __restrict__ x, const float* __restrict__ h,
    const float* __restrict__ m,
    uint16_t* __restrict__ P, uint16_t* __restrict__ P2)
{
    int bid = blockIdx.x;
    int t = threadIdx.x;

    if (bid < 112) {
        // W: fp32 [14][32][64] -> bf16 Wp[gp][col][slot^swz][k&7]
        // B-frag (16x16x32): lane l holds B[k=(l>>4)*8+e][col=l&15].
        int idx = bid * 256 + t;                    // 14*32*64 = 28672
        int g   = idx >> 11;
        int k   = (idx >> 6) & 31;
        int col = idx & 63;
        uint16_t v = f2bf(Wf[idx]);                 // Wf[g][k][col]
        int gp = g >> 1;
        int sl = ((g & 1) << 2) | (k >> 3);
        int ph = sl ^ (col & 7);
        Wp[((gp * 64 + col) * 64) + ph * 8 + (k & 7)] = v;
        return;
    }
    bid -= 112;

    // pack: state [B][N][F] fp32 -> dst[rowbase + b*32 + f][n] bf16
    const float* src; uint16_t* dst; int rowbase, b, n0;
    if (bid < 512) {
        int tensor = bid >> 8;
        src = tensor ? h : x; dst = P; rowbase = tensor * 128;
        b = (bid >> 6) & 3; n0 = (bid & 63) * 64;
    } else {
        int q = bid - 512;
        src = m; dst = P2; rowbase = 128;
        b = q >> 6; n0 = (q & 63) * 64;
    }
    __shared__ uint16_t tl[32][65];
    {
        int i = t >> 2, ch = t & 3;       // node i (0..63), f-chunk ch (8 floats)
        size_t idx = ((size_t)(b * NN + n0 + i)) * FF + ch * 8;
        float4 v0 = *(const float4*)(src + idx);
        float4 v1 = *(const float4*)(src + idx + 4);
        uint16_t e[8] = { f2bf(v0.x), f2bf(v0.y), f2bf(v0.z), f2bf(v0.w),
                          f2bf(v1.x), f2bf(v1.y), f2bf(v1.z), f2bf(v1.w) };
        #pragma unroll
        for (int k = 0; k < 8; k++) tl[ch * 8 + k][i] = e[k];
    }
    __syncthreads();
    {
        int f = t >> 3, ch = t & 7;
        union { uint4 u; uint16_t e[8]; } v;
        #pragma unroll
        for (int k = 0; k < 8; k++) v.e[k] = tl[f][ch * 8 + k];
        size_t row = (size_t)(rowbase + b * 32 + f);
        *(uint4*)(dst + row * NN + n0 + ch * 8) = v.u;
    }
}

// ======================================================================
// mega1: GEMM (adj fp32 x P bf16, full K=4096) + dense(MFMA) + GLU + LSTM.
// Block = (batch b, 16 nodes); 4 waves; wave w owns c'-rows w*16..+15.
// K-loop: BK=128 (4 x BK32 sub-buffers), staging/swizzle/ds_read/MFMA
// byte-identical to the validated R10 gemm (fp32-A reg-staging branch for A,
// global_load_lds for B).  acc (fp32) scatters into AL[c'][node] — exactly
// the layout the validated fuse phase-2/3 consumes — then that code runs
// verbatim.  Deletes the Cbuf roundtrip + separate fuse launch.
// ======================================================================
__global__ __launch_bounds__(256, 3) void mega1_kernel(
    const float* __restrict__ adj,    // [4096][4096] fp32
    const uint16_t* __restrict__ P,   // [256][4096] bf16 (x 0..127, h 128..255)
    const uint16_t* __restrict__ Wp,  // packed W (prep)
    const float* __restrict__ bf_,
    const float* __restrict__ cf,
    float* __restrict__ cnew, uint16_t* __restrict__ S2t)
{
    __shared__ __align__(16) uint16_t aLb[4][16 * 32];  // 4 KB
    __shared__ __align__(16) uint16_t bLb[4][64 * 32];  // 16 KB
    __shared__ float    AL[64 * 17];                    // 4.4 KB
    __shared__ float    SX[4][64][9];                   // 9.2 KB
    __shared__ uint16_t H1[32 * 18];                    // 1.2 KB

    int t = threadIdx.x;
    int bid = blockIdx.x;              // 1024
    int b = bid >> 8, n0 = (bid & 255) * 16;
    int lane = t & 63, w = t >> 6;
    int lm = lane & 15, lk = lane >> 4;
    int j = lm, kg = lk;
    int ej = t & 15, erow = (t >> 4) & 15;

    // c prefetch (in flight under the K-loop)
    float cv[2];
    #pragma unroll
    for (int hh = 0; hh < 2; hh++)
        cv[hh] = cf[((size_t)(b * NN + n0 + erow)) * FF + ej + hh * 16];

    // ---- K-loop (validated R10 structure; A = fp32 adj, B = P bf16) ----
    int aq = t >> 6, apos = (t & 63) * 16;
    int arow = apos >> 6;
    int aslot = ((apos >> 4) & 3) ^ ((arow >> 1) & 3);
    int bpos = t * 16;
    int brow = bpos >> 6;
    int bslot = ((bpos >> 4) & 3) ^ ((brow >> 1) & 3);
    int bcrow = brow + ((brow < 32) ? b * 32 : 96 + b * 32);  // 128+b*32+(brow-32)
    int rA = lm;          int swA = (lk ^ ((rA >> 1) & 3)) * 8;
    int rB = w * 16 + lm; int swB = (lk ^ ((rB >> 1) & 3)) * 8;

    f32x4 acc = {};
    for (int kk = 0; kk < 4096; kk += 128) {
        {   // A: fp32 -> bf16 reg staging (R10 isf32A formulas)
            size_t aidx = (size_t)(n0 + arow) * 4096 + kk + aq * 32 + aslot * 8;
            union { uint4 u[2]; float f[8]; } va;
            va.u[0] = *(const uint4*)(adj + aidx);
            va.u[1] = *(const uint4*)(adj + aidx + 4);
            union { uint4 u; uint16_t e[8]; } sa;
            #pragma unroll
            for (int k = 0; k < 8; k++) sa.e[k] = f2bf(va.f[k]);
            *(uint4*)((char*)aLb[aq] + apos) = sa.u;
        }
        #pragma unroll
        for (int q = 0; q < 4; q++) {   // B: 4 bufs x 256 x 16B via global_load_lds
            size_t bidx = (size_t)bcrow * 4096 + kk + q * 32 + bslot * 8;
            __builtin_amdgcn_global_load_lds((as1_cvoid*)(P + bidx),
                (as3_void*)((char*)bLb[q] + bpos), 16, 0, 0);
        }
        __syncthreads();
        #pragma unroll
        for (int q = 0; q < 4; q++) {
            s16x8 af = *(const s16x8*)(aLb[q] + rA * 32 + swA);
            s16x8 bf = *(const s16x8*)(bLb[q] + rB * 32 + swB);
            acc = __builtin_amdgcn_mfma_f32_16x16x32_bf16(af, bf, acc, 0, 0, 0);
        }
        __syncthreads();
    }

    // scatter acc -> AL[c'][node]: lane holds D[c'=w*16+lm][node=lk*4+r]
    {
        int cp = w * 16 + lm;
        #pragma unroll
        for (int r = 0; r < 4; r++)
            AL[cp * 17 + lk * 4 + r] = acc[r];
    }
    __syncthreads();

    // ---- fuse phase 2: wave w = gate-pair w (verbatim from validated fuse1) ----
    s16x8 a_ax, a_ah;
    #pragma unroll
    for (int e = 0; e < 8; e++) {
        int k = kg * 8 + e;
        a_ax[e] = (short)f2bf(AL[k * 17 + j]);
        a_ah[e] = (short)f2bf(AL[(32 + k) * 17 + j]);
    }
    {
        int p = w;                                // gate-pair: even=ax, odd=ah
        int g0 = p * 2, g1 = p * 2 + 1;
        f32x4 ac0[4] = {}, ac1[4] = {};
        #pragma unroll
        for (int ct = 0; ct < 4; ct++) {
            int col = ct * 16 + j;
            int ph0 = (kg)     ^ (col & 7);
            int ph1 = (4 + kg) ^ (col & 7);
            s16x8 b0 = *(const s16x8*)(Wp + (p * 64 + col) * 64 + ph0 * 8);
            s16x8 b1 = *(const s16x8*)(Wp + (p * 64 + col) * 64 + ph1 * 8);
            ac0[ct] = __builtin_amdgcn_mfma_f32_16x16x32_bf16(a_ax, b0, ac0[ct], 0, 0, 0);
            ac1[ct] = __builtin_amdgcn_mfma_f32_16x16x32_bf16(a_ah, b1, ac1[ct], 0, 0, 0);
        }
        #pragma unroll
        for (int hh = 0; hh < 2; hh++)
            #pragma unroll
            for (int r = 0; r < 4; r++) {
                float z0l = ac0[hh][r]     + bf_[g0 * 64 + hh * 16 + j];
                float z0r = ac0[2 + hh][r] + bf_[g0 * 64 + 32 + hh * 16 + j];
                float z1l = ac1[hh][r]     + bf_[g1 * 64 + hh * 16 + j];
                float z1r = ac1[2 + hh][r] + bf_[g1 * 64 + 32 + hh * 16 + j];
                SX[p][lane][hh * 4 + r] = z0l * sig_acc(z0r) + z1l * sig_acc(z1r);
            }
    }
    __syncthreads();

    // ---- fuse phase 3: LSTM update; thread t -> element (erow, ej) ----
    {
        int pl = ((erow >> 2) << 4) | ej;         // producer lane
        int ridx = erow & 3;
        #pragma unroll
        for (int hh = 0; hh < 2; hh++) {
            float s0 = SX[0][pl][hh * 4 + ridx];
            float s1 = SX[1][pl][hh * 4 + ridx];
            float s2 = SX[2][pl][hh * 4 + ridx];
            float s3 = SX[3][pl][hh * 4 + ridx];
            float fg = sig_acc(s0), ig = sig_acc(s1);
            float cc = tanhf(s2),   og = sig_acc(s3);
            float cn = fg * cv[hh] + ig * cc;
            size_t gidx = ((size_t)(b * NN + n0 + erow)) * FF + ej + hh * 16;
            cnew[gidx] = cn;
            H1[(ej + hh * 16) * 18 + erow] = f2bf(og * tanhf(cn));
        }
    }
    __syncthreads();
    if (t < 64) {   // pack h1 -> P2 rows b*32+f (phase-2 B operand, rows 0..127)
        int f = t >> 1, half = t & 1;
        union { uint4 u; uint16_t e[8]; } v;
        #pragma unroll
        for (int k = 0; k < 8; k++) v.e[k] = H1[f * 18 + half * 8 + k];
        *(uint4*)(S2t + ((size_t)(b * 32 + f)) * NN + n0 + half * 8) = v.u;
    }
}

// ======================================================================
// mega2: same K-loop (B = P2: h1 rows 0..127, m rows 128..255) + fuse2
// phase 2/3 (3 gate-pairs; wave 3 idles only in the W-MFMA).
// ======================================================================
__global__ __launch_bounds__(256, 3) void mega2_kernel(
    const float* __restrict__ adj,
    const uint16_t* __restrict__ P2,
    const uint16_t* __restrict__ Wp,
    const float* __restrict__ bf_,
    const float* __restrict__ mf,
    float* __restrict__ hnew, float* __restrict__ mnew)
{
    __shared__ __align__(16) uint16_t aLb[4][16 * 32];
    __shared__ __align__(16) uint16_t bLb[4][64 * 32];
    __shared__ float AL[64 * 17];
    __shared__ float SX[3][64][9];

    int t = threadIdx.x;
    int bid = blockIdx.x;
    int b = bid >> 8, n0 = (bid & 255) * 16;
    int lane = t & 63, w = t >> 6;
    int lm = lane & 15, lk = lane >> 4;
    int j = lm, kg = lk;
    int ej = t & 15, erow = (t >> 4) & 15;

    float mv[2];
    #pragma unroll
    for (int hh = 0; hh < 2; hh++)
        mv[hh] = mf[((size_t)(b * NN + n0 + erow)) * FF + ej + hh * 16];

    int aq = t >> 6, apos = (t & 63) * 16;
    int arow = apos >> 6;
    int aslot = ((apos >> 4) & 3) ^ ((arow >> 1) & 3);
    int bpos = t * 16;
    int brow = bpos >> 6;
    int bslot = ((bpos >> 4) & 3) ^ ((brow >> 1) & 3);
    int bcrow = brow + ((brow < 32) ? b * 32 : 96 + b * 32);
    int rA = lm;          int swA = (lk ^ ((rA >> 1) & 3)) * 8;
    int rB = w * 16 + lm; int swB = (lk ^ ((rB >> 1) & 3)) * 8;

    f32x4 acc = {};
    for (int kk = 0; kk < 4096; kk += 128) {
        {
            size_t aidx = (size_t)(n0 + arow) * 4096 + kk + aq * 32 + aslot * 8;
            union { uint4 u[2]; float f[8]; } va;
            va.u[0] = *(const uint4*)(adj + aidx);
            va.u[1] = *(const uint4*)(adj + aidx + 4);
            union { uint4 u; uint16_t e[8]; } sa;
            #pragma unroll
            for (int k = 0; k < 8; k++) sa.e[k] = f2bf(va.f[k]);
            *(uint4*)((char*)aLb[aq] + apos) = sa.u;
        }
        #pragma unroll
        for (int q = 0; q < 4; q++) {
            size_t bidx = (size_t)bcrow * 4096 + kk + q * 32 + bslot * 8;
            __builtin_amdgcn_global_load_lds((as1_cvoid*)(P2 + bidx),
                (as3_void*)((char*)bLb[q] + bpos), 16, 0, 0);
        }
        __syncthreads();
        #pragma unroll
        for (int q = 0; q < 4; q++) {
            s16x8 af = *(const s16x8*)(aLb[q] + rA * 32 + swA);
            s16x8 bf = *(const s16x8*)(bLb[q] + rB * 32 + swB);
            acc = __builtin_amdgcn_mfma_f32_16x16x32_bf16(af, bf, acc, 0, 0, 0);
        }
        __syncthreads();
    }

    {
        int cp = w * 16 + lm;
        #pragma unroll
        for (int r = 0; r < 4; r++)
            AL[cp * 17 + lk * 4 + r] = acc[r];
    }
    __syncthreads();

    if (w < 3) {
        s16x8 a_h1, a_m;
        #pragma unroll
        for (int e = 0; e < 8; e++) {
            int k = kg * 8 + e;
            a_h1[e] = (short)f2bf(AL[k * 17 + j]);
            a_m[e]  = (short)f2bf(AL[(32 + k) * 17 + j]);
        }
        const uint16_t* WpG = Wp + 4 * 64 * 64;   // gate-pairs 4..6 (gates 8..13)
        const float*    bG  = bf_ + 512;
        int p = w;
        int g0 = p * 2, g1 = p * 2 + 1;           // even: ah1, odd: am
        f32x4 ac0[4] = {}, ac1[4] = {};
        #pragma unroll
        for (int ct = 0; ct < 4; ct++) {
            int col = ct * 16 + j;
            int ph0 = (kg)     ^ (col & 7);
            int ph1 = (4 + kg) ^ (col & 7);
            s16x8 b0 = *(const s16x8*)(WpG + (p * 64 + col) * 64 + ph0 * 8);
            s16x8 b1 = *(const s16x8*)(WpG + (p * 64 + col) * 64 + ph1 * 8);
            ac0[ct] = __builtin_amdgcn_mfma_f32_16x16x32_bf16(a_h1, b0, ac0[ct], 0, 0, 0);
            ac1[ct] = __builtin_amdgcn_mfma_f32_16x16x32_bf16(a_m, b1, ac1[ct], 0, 0, 0);
        }
        #pragma unroll
        for (int hh = 0; hh < 2; hh++)
            #pragma unroll
            for (int r = 0; r < 4; r++) {
                float z0l = ac0[hh][r]     + bG[g0 * 64 + hh * 16 + j];
                float z0r = ac0[2 + hh][r] + bG[g0 * 64 + 32 + hh * 16 + j];
                float z1l = ac1[hh][r]     + bG[g1 * 64 + hh * 16 + j];
                float z1r = ac1[2 + hh][r] + bG[g1 * 64 + 32 + hh * 16 + j];
                SX[p][lane][hh * 4 + r] = z0l * sig_acc(z0r) + z1l * sig_acc(z1r);
            }
    }
    __syncthreads();

    {
        int pl = ((erow >> 2) << 4) | ej;
        int ridx = erow & 3;
        #pragma unroll
        for (int hh = 0; hh < 2; hh++) {
            float s0 = SX[0][pl][hh * 4 + ridx];
            float s1 = SX[1][pl][hh * 4 + ridx];
            float s2 = SX[2][pl][hh * 4 + ridx];
            float i2 = sig_acc(s0);
            float gg = sig_acc(s1);
            float o2 = sig_acc(s2);
            float mn = i2 * mv[hh] + (1.0f - i2) * gg;
            size_t gidx = ((size_t)(b * NN + n0 + erow)) * FF + ej + hh * 16;
            mnew[gidx] = mn;
            hnew[gidx] = mn * o2;
        }
    }
}

extern "C" void kernel_launch(void* const* d_in, const int* in_sizes, int n_in,
                              void* d_out, int out_size, void* d_ws, size_t ws_size,
                              hipStream_t stream) {
    (void)in_sizes; (void)n_in; (void)out_size;
    const float* x   = (const float*)d_in[0];
    const float* h   = (const float*)d_in[1];
    const float* c   = (const float*)d_in[2];
    const float* m   = (const float*)d_in[3];
    const float* adj = (const float*)d_in[4];
    const float* W   = (const float*)d_in[5];
    const float* bb  = (const float*)d_in[6];
    float* out = (float*)d_out;

    char* ws = (char*)d_ws;
    uint16_t* P    = (uint16_t*)ws;                  // 2 MB phase-1 B (x,h)
    uint16_t* P2   = (uint16_t*)(ws + (2u << 20));   // 2 MB phase-2 B (h1,m)
    uint16_t* Wp   = (uint16_t*)(ws + (4u << 20));   // 112 KB packed W

    if (ws_size < (6u << 20)) return;   // harness ws is ~268MB; safety only

    // prep: W pack, x/h -> P, m -> P2 rows 128..255 (input-only, one launch)
    prep_kernel<<<880, 256, 0, stream>>>(W, Wp, x, h, m, P, P2);

    // phase 1: GEMM(adj x P) + GLU + LSTM; c_new + h1 -> P2 rows 0..127
    mega1_kernel<<<1024, 256, 0, stream>>>(adj, P, Wp, bb, c, out + BNF, P2);
    // phase 2: GEMM(adj x P2) + GLU + memory update; h_new, m_new
    mega2_kernel<<<1024, 256, 0, stream>>>(adj, P2, Wp, bb, m, out, out + 2 * BNF);
}

// Round 12
// 172.925 us; speedup vs baseline: 1.4159x; 1.0830x over previous
//
#include <hip/hip_runtime.h>
#include <stdint.h>

typedef __attribute__((ext_vector_type(4))) float f32x4;
typedef __attribute__((ext_vector_type(8))) short s16x8;

#define BB 4
#define NN 4096
#define FF 32
#define BNF (BB*NN*FF)   // 524288

typedef __attribute__((address_space(3))) void       as3_void;
typedef const __attribute__((address_space(1))) void as1_cvoid;

// ---------- bf16 helpers ----------
static __device__ __forceinline__ float bf2f(uint16_t u) {
    union { uint32_t i; float f; } v; v.i = ((uint32_t)u) << 16; return v.f;
}
static __device__ __forceinline__ uint16_t f2bf(float f) {
    union { float f; uint32_t i; } v; v.f = f;
    uint32_t r = v.i + 0x7FFFu + ((v.i >> 16) & 1u);
    return (uint16_t)(r >> 16);
}
static __device__ __forceinline__ float sig_acc(float x) { return 1.0f / (1.0f + expf(-x)); }

// ======================================================================
// prep: ONE launch for all input-only work (R7-validated structure).
//   blocks [0, cvtN):          adj fp32 -> bf16  (cvtN = 8192 or 0)
//   blocks [cvtN, cvtN+112):   pack W -> Wp (MFMA B-frag layout, swizzled)
//   blocks [cvtN+112, +768):   pack x,h -> P rows 0..255; m -> P2 rows 128..255
// ======================================================================
__global__ __launch_bounds__(256) void prep_kernel(
    const float* __restrict__ adj, uint16_t* __restrict__ adjb, int cvtN,
    const float* __restrict__ Wf, uint16_t* __restrict__ Wp,
    const float* __restrict__ x, const float* __restrict__ h,
    const float* __restrict__ m,
    uint16_t* __restrict__ P, uint16_t* __restrict__ P2)
{
    int bid = blockIdx.x;
    int t = threadIdx.x;

    if (bid < cvtN) {
        size_t i = ((size_t)bid * 256 + t) * 8;
        float4 v0 = *(const float4*)(adj + i);
        float4 v1 = *(const float4*)(adj + i + 4);
        union { uint4 u; uint16_t e[8]; } o;
        o.e[0] = f2bf(v0.x); o.e[1] = f2bf(v0.y); o.e[2] = f2bf(v0.z); o.e[3] = f2bf(v0.w);
        o.e[4] = f2bf(v1.x); o.e[5] = f2bf(v1.y); o.e[6] = f2bf(v1.z); o.e[7] = f2bf(v1.w);
        *(uint4*)(adjb + i) = o.u;
        return;
    }
    bid -= cvtN;

    if (bid < 112) {
        // W: fp32 [14][32][64] -> bf16 Wp[gp][col][slot^swz][k&7]
        int idx = bid * 256 + t;                    // 14*32*64 = 28672
        int g   = idx >> 11;
        int k   = (idx >> 6) & 31;
        int col = idx & 63;
        uint16_t v = f2bf(Wf[idx]);                 // Wf[g][k][col]
        int gp = g >> 1;
        int sl = ((g & 1) << 2) | (k >> 3);
        int ph = sl ^ (col & 7);
        Wp[((gp * 64 + col) * 64) + ph * 8 + (k & 7)] = v;
        return;
    }
    bid -= 112;

    // pack: state [B][N][F] fp32 -> dst[rowbase + b*32 + f][n] bf16
    const float* src; uint16_t* dst; int rowbase, b, n0;
    if (bid < 512) {
        int tensor = bid >> 8;
        src = tensor ? h : x; dst = P; rowbase = tensor * 128;
        b = (bid >> 6) & 3; n0 = (bid & 63) * 64;
    } else {
        int q = bid - 512;
        src = m; dst = P2; rowbase = 128;
        b = q >> 6; n0 = (q & 63) * 64;
    }
    __shared__ uint16_t tl[32][65];
    {
        int i = t >> 2, ch = t & 3;       // node i (0..63), f-chunk ch (8 floats)
        size_t idx = ((size_t)(b * NN + n0 + i)) * FF + ch * 8;
        float4 v0 = *(const float4*)(src + idx);
        float4 v1 = *(const float4*)(src + idx + 4);
        uint16_t e[8] = { f2bf(v0.x), f2bf(v0.y), f2bf(v0.z), f2bf(v0.w),
                          f2bf(v1.x), f2bf(v1.y), f2bf(v1.z), f2bf(v1.w) };
        #pragma unroll
        for (int k = 0; k < 8; k++) tl[ch * 8 + k][i] = e[k];
    }
    __syncthreads();
    {
        int f = t >> 3, ch = t & 7;
        union { uint4 u; uint16_t e[8]; } v;
        #pragma unroll
        for (int k = 0; k < 8; k++) v.e[k] = tl[f][ch * 8 + k];
        size_t row = (size_t)(rowbase + b * 32 + f);
        *(uint4*)(dst + row * NN + n0 + ch * 8) = v.u;
    }
}

// ======================================================================
// mega1: GEMM (adj x P, full K=4096) + dense(MFMA) + GLU + LSTM.
// Block = (batch b, 32 nodes); 512 blocks (2/CU).  4 waves; wave w owns
// c'-rows w*16..+15 for BOTH 16-node halves (acc0 = nodes 0..15,
// acc1 = nodes 16..31; swizzle const identical since ((16+lm)>>1)&3 ==
// ((lm)>>1)&3).  K-loop staging/swizzle/ds_read/MFMA formulas carried
// verbatim from the validated R10/R11 scheme; 32-node tile halves the
// per-output B re-read (512 blocks x 512KB = 256MB vs R11's 512MB).
// A is bf16 (tier-A cvt) -> 128MB L3-served vs 256MB fp32.
// Fuse phase-2/3 runs verbatim per 16-node half.
// ======================================================================
__global__ __launch_bounds__(256, 2) void mega1_kernel(
    const void* __restrict__ Av,      // adj: bf16 (isf32A=0) or fp32 (isf32A=1)
    const uint16_t* __restrict__ P,   // [256][4096] bf16 (x 0..127, h 128..255)
    const uint16_t* __restrict__ Wp,  // packed W (prep)
    const float* __restrict__ bf_,
    const float* __restrict__ cf,
    float* __restrict__ cnew, uint16_t* __restrict__ S2t, int isf32A)
{
    __shared__ __align__(16) uint16_t aLb[4][32 * 32];  // 8 KB
    __shared__ __align__(16) uint16_t bLb[4][64 * 32];  // 16 KB
    __shared__ float    AL[64 * 33];                    // 8.4 KB
    __shared__ float    SX[4][64][9];                   // 9.2 KB
    __shared__ uint16_t H1[32 * 18];                    // 1.2 KB

    int t = threadIdx.x;
    int bid = blockIdx.x;              // 512
    int b = bid >> 7, n0 = (bid & 127) * 32;
    int lane = t & 63, w = t >> 6;
    int lm = lane & 15, lk = lane >> 4;
    int j = lm, kg = lk;
    int ej = t & 15, erow = (t >> 4) & 15;

    const uint16_t* A16 = (const uint16_t*)Av;
    const float*    Af  = (const float*)Av;

    // c prefetch (in flight under the K-loop)
    float cv[2][2];
    #pragma unroll
    for (int gh = 0; gh < 2; gh++)
        #pragma unroll
        for (int hh = 0; hh < 2; hh++)
            cv[gh][hh] = cf[((size_t)(b * NN + n0 + gh * 16 + erow)) * FF + ej + hh * 16];

    // A slot constants: 2 slots/thread (4 bufs x 32 rows x 4 slots = 512)
    int aq0 = t >> 7,        ap0 = (t & 127) * 16;
    int ar0 = ap0 >> 6,      asl0 = ((ap0 >> 4) & 3) ^ ((ar0 >> 1) & 3);
    int gs1 = t + 256;
    int aq1 = gs1 >> 7,      ap1 = (gs1 & 127) * 16;
    int ar1 = ap1 >> 6,      asl1 = ((ap1 >> 4) & 3) ^ ((ar1 >> 1) & 3);
    // B constants (verbatim R11)
    int bpos = t * 16;
    int brow = bpos >> 6;
    int bslot = ((bpos >> 4) & 3) ^ ((brow >> 1) & 3);
    int bcrow = brow + ((brow < 32) ? b * 32 : 96 + b * 32);  // 128+b*32+(brow-32)
    int rB = w * 16 + lm; int swB = (lk ^ ((rB >> 1) & 3)) * 8;
    int swA = (lk ^ ((lm >> 1) & 3)) * 8;     // same for node halves 0..15 / 16..31

    f32x4 acc0 = {}, acc1 = {};
    for (int kk = 0; kk < 4096; kk += 128) {
        if (!isf32A) {
            __builtin_amdgcn_global_load_lds(
                (as1_cvoid*)(A16 + (size_t)(n0 + ar0) * 4096 + kk + aq0 * 32 + asl0 * 8),
                (as3_void*)((char*)aLb[aq0] + ap0), 16, 0, 0);
            __builtin_amdgcn_global_load_lds(
                (as1_cvoid*)(A16 + (size_t)(n0 + ar1) * 4096 + kk + aq1 * 32 + asl1 * 8),
                (as3_void*)((char*)aLb[aq1] + ap1), 16, 0, 0);
        } else {
            union { uint4 u; uint16_t e[8]; } sa0, sa1;
            {
                size_t aidx = (size_t)(n0 + ar0) * 4096 + kk + aq0 * 32 + asl0 * 8;
                union { uint4 u[2]; float f[8]; } va;
                va.u[0] = *(const uint4*)(Af + aidx);
                va.u[1] = *(const uint4*)(Af + aidx + 4);
                #pragma unroll
                for (int k = 0; k < 8; k++) sa0.e[k] = f2bf(va.f[k]);
            }
            {
                size_t aidx = (size_t)(n0 + ar1) * 4096 + kk + aq1 * 32 + asl1 * 8;
                union { uint4 u[2]; float f[8]; } va;
                va.u[0] = *(const uint4*)(Af + aidx);
                va.u[1] = *(const uint4*)(Af + aidx + 4);
                #pragma unroll
                for (int k = 0; k < 8; k++) sa1.e[k] = f2bf(va.f[k]);
            }
            *(uint4*)((char*)aLb[aq0] + ap0) = sa0.u;
            *(uint4*)((char*)aLb[aq1] + ap1) = sa1.u;
        }
        #pragma unroll
        for (int q = 0; q < 4; q++) {   // B: 4 bufs x 256 x 16B via global_load_lds
            size_t bidx = (size_t)bcrow * 4096 + kk + q * 32 + bslot * 8;
            __builtin_amdgcn_global_load_lds((as1_cvoid*)(P + bidx),
                (as3_void*)((char*)bLb[q] + bpos), 16, 0, 0);
        }
        __syncthreads();
        #pragma unroll
        for (int q = 0; q < 4; q++) {
            s16x8 af0 = *(const s16x8*)(aLb[q] + lm * 32 + swA);
            s16x8 af1 = *(const s16x8*)(aLb[q] + (16 + lm) * 32 + swA);
            s16x8 bf  = *(const s16x8*)(bLb[q] + rB * 32 + swB);
            acc0 = __builtin_amdgcn_mfma_f32_16x16x32_bf16(af0, bf, acc0, 0, 0, 0);
            acc1 = __builtin_amdgcn_mfma_f32_16x16x32_bf16(af1, bf, acc1, 0, 0, 0);
        }
        __syncthreads();
    }

    // scatter acc -> AL[c'][node 0..31]: lane holds D[c'=w*16+lm][node=half*16+lk*4+r]
    {
        int cp = w * 16 + lm;
        #pragma unroll
        for (int r = 0; r < 4; r++) {
            AL[cp * 33 + lk * 4 + r]      = acc0[r];
            AL[cp * 33 + 16 + lk * 4 + r] = acc1[r];
        }
    }
    __syncthreads();

    // ---- fuse phase 2/3 per 16-node half (verbatim validated fuse1) ----
    for (int gh = 0; gh < 2; gh++) {
        int colb = gh * 16;
        s16x8 a_ax, a_ah;
        #pragma unroll
        for (int e = 0; e < 8; e++) {
            int k = kg * 8 + e;
            a_ax[e] = (short)f2bf(AL[k * 33 + colb + j]);
            a_ah[e] = (short)f2bf(AL[(32 + k) * 33 + colb + j]);
        }
        {
            int p = w;                                // gate-pair: even=ax, odd=ah
            int g0 = p * 2, g1 = p * 2 + 1;
            f32x4 ac0[4] = {}, ac1[4] = {};
            #pragma unroll
            for (int ct = 0; ct < 4; ct++) {
                int col = ct * 16 + j;
                int ph0 = (kg)     ^ (col & 7);
                int ph1 = (4 + kg) ^ (col & 7);
                s16x8 b0 = *(const s16x8*)(Wp + (p * 64 + col) * 64 + ph0 * 8);
                s16x8 b1 = *(const s16x8*)(Wp + (p * 64 + col) * 64 + ph1 * 8);
                ac0[ct] = __builtin_amdgcn_mfma_f32_16x16x32_bf16(a_ax, b0, ac0[ct], 0, 0, 0);
                ac1[ct] = __builtin_amdgcn_mfma_f32_16x16x32_bf16(a_ah, b1, ac1[ct], 0, 0, 0);
            }
            #pragma unroll
            for (int hh = 0; hh < 2; hh++)
                #pragma unroll
                for (int r = 0; r < 4; r++) {
                    float z0l = ac0[hh][r]     + bf_[g0 * 64 + hh * 16 + j];
                    float z0r = ac0[2 + hh][r] + bf_[g0 * 64 + 32 + hh * 16 + j];
                    float z1l = ac1[hh][r]     + bf_[g1 * 64 + hh * 16 + j];
                    float z1r = ac1[2 + hh][r] + bf_[g1 * 64 + 32 + hh * 16 + j];
                    SX[p][lane][hh * 4 + r] = z0l * sig_acc(z0r) + z1l * sig_acc(z1r);
                }
        }
        __syncthreads();
        {
            int pl = ((erow >> 2) << 4) | ej;         // producer lane
            int ridx = erow & 3;
            #pragma unroll
            for (int hh = 0; hh < 2; hh++) {
                float s0 = SX[0][pl][hh * 4 + ridx];
                float s1 = SX[1][pl][hh * 4 + ridx];
                float s2 = SX[2][pl][hh * 4 + ridx];
                float s3 = SX[3][pl][hh * 4 + ridx];
                float fg = sig_acc(s0), ig = sig_acc(s1);
                float cc = tanhf(s2),   og = sig_acc(s3);
                float cn = fg * cv[gh][hh] + ig * cc;
                size_t gidx = ((size_t)(b * NN + n0 + gh * 16 + erow)) * FF + ej + hh * 16;
                cnew[gidx] = cn;
                H1[(ej + hh * 16) * 18 + erow] = f2bf(og * tanhf(cn));
            }
        }
        __syncthreads();
        if (t < 64) {   // pack h1 -> P2 rows b*32+f (phase-2 B operand)
            int f = t >> 1, half = t & 1;
            union { uint4 u; uint16_t e[8]; } v;
            #pragma unroll
            for (int k = 0; k < 8; k++) v.e[k] = H1[f * 18 + half * 8 + k];
            *(uint4*)(S2t + ((size_t)(b * 32 + f)) * NN + n0 + gh * 16 + half * 8) = v.u;
        }
        __syncthreads();
    }
}

// ======================================================================
// mega2: same K-loop (B = P2: h1 rows 0..127, m rows 128..255) + fuse2
// phase 2/3 per half (3 gate-pairs; wave 3 idles only in the W-MFMA).
// ======================================================================
__global__ __launch_bounds__(256, 2) void mega2_kernel(
    const void* __restrict__ Av,
    const uint16_t* __restrict__ P2,
    const uint16_t* __restrict__ Wp,
    const float* __restrict__ bf_,
    const float* __restrict__ mf,
    float* __restrict__ hnew, float* __restrict__ mnew, int isf32A)
{
    __shared__ __align__(16) uint16_t aLb[4][32 * 32];
    __shared__ __align__(16) uint16_t bLb[4][64 * 32];
    __shared__ float AL[64 * 33];
    __shared__ float SX[3][64][9];

    int t = threadIdx.x;
    int bid = blockIdx.x;              // 512
    int b = bid >> 7, n0 = (bid & 127) * 32;
    int lane = t & 63, w = t >> 6;
    int lm = lane & 15, lk = lane >> 4;
    int j = lm, kg = lk;
    int ej = t & 15, erow = (t >> 4) & 15;

    const uint16_t* A16 = (const uint16_t*)Av;
    const float*    Af  = (const float*)Av;

    float mv[2][2];
    #pragma unroll
    for (int gh = 0; gh < 2; gh++)
        #pragma unroll
        for (int hh = 0; hh < 2; hh++)
            mv[gh][hh] = mf[((size_t)(b * NN + n0 + gh * 16 + erow)) * FF + ej + hh * 16];

    int aq0 = t >> 7,        ap0 = (t & 127) * 16;
    int ar0 = ap0 >> 6,      asl0 = ((ap0 >> 4) & 3) ^ ((ar0 >> 1) & 3);
    int gs1 = t + 256;
    int aq1 = gs1 >> 7,      ap1 = (gs1 & 127) * 16;
    int ar1 = ap1 >> 6,      asl1 = ((ap1 >> 4) & 3) ^ ((ar1 >> 1) & 3);
    int bpos = t * 16;
    int brow = bpos >> 6;
    int bslot = ((bpos >> 4) & 3) ^ ((brow >> 1) & 3);
    int bcrow = brow + ((brow < 32) ? b * 32 : 96 + b * 32);
    int rB = w * 16 + lm; int swB = (lk ^ ((rB >> 1) & 3)) * 8;
    int swA = (lk ^ ((lm >> 1) & 3)) * 8;

    f32x4 acc0 = {}, acc1 = {};
    for (int kk = 0; kk < 4096; kk += 128) {
        if (!isf32A) {
            __builtin_amdgcn_global_load_lds(
                (as1_cvoid*)(A16 + (size_t)(n0 + ar0) * 4096 + kk + aq0 * 32 + asl0 * 8),
                (as3_void*)((char*)aLb[aq0] + ap0), 16, 0, 0);
            __builtin_amdgcn_global_load_lds(
                (as1_cvoid*)(A16 + (size_t)(n0 + ar1) * 4096 + kk + aq1 * 32 + asl1 * 8),
                (as3_void*)((char*)aLb[aq1] + ap1), 16, 0, 0);
        } else {
            union { uint4 u; uint16_t e[8]; } sa0, sa1;
            {
                size_t aidx = (size_t)(n0 + ar0) * 4096 + kk + aq0 * 32 + asl0 * 8;
                union { uint4 u[2]; float f[8]; } va;
                va.u[0] = *(const uint4*)(Af + aidx);
                va.u[1] = *(const uint4*)(Af + aidx + 4);
                #pragma unroll
                for (int k = 0; k < 8; k++) sa0.e[k] = f2bf(va.f[k]);
            }
            {
                size_t aidx = (size_t)(n0 + ar1) * 4096 + kk + aq1 * 32 + asl1 * 8;
                union { uint4 u[2]; float f[8]; } va;
                va.u[0] = *(const uint4*)(Af + aidx);
                va.u[1] = *(const uint4*)(Af + aidx + 4);
                #pragma unroll
                for (int k = 0; k < 8; k++) sa1.e[k] = f2bf(va.f[k]);
            }
            *(uint4*)((char*)aLb[aq0] + ap0) = sa0.u;
            *(uint4*)((char*)aLb[aq1] + ap1) = sa1.u;
        }
        #pragma unroll
        for (int q = 0; q < 4; q++) {
            size_t bidx = (size_t)bcrow * 4096 + kk + q * 32 + bslot * 8;
            __builtin_amdgcn_global_load_lds((as1_cvoid*)(P2 + bidx),
                (as3_void*)((char*)bLb[q] + bpos), 16, 0, 0);
        }
        __syncthreads();
        #pragma unroll
        for (int q = 0; q < 4; q++) {
            s16x8 af0 = *(const s16x8*)(aLb[q] + lm * 32 + swA);
            s16x8 af1 = *(const s16x8*)(aLb[q] + (16 + lm) * 32 + swA);
            s16x8 bf  = *(const s16x8*)(bLb[q] + rB * 32 + swB);
            acc0 = __builtin_amdgcn_mfma_f32_16x16x32_bf16(af0, bf, acc0, 0, 0, 0);
            acc1 = __builtin_amdgcn_mfma_f32_16x16x32_bf16(af1, bf, acc1, 0, 0, 0);
        }
        __syncthreads();
    }

    {
        int cp = w * 16 + lm;
        #pragma unroll
        for (int r = 0; r < 4; r++) {
            AL[cp * 33 + lk * 4 + r]      = acc0[r];
            AL[cp * 33 + 16 + lk * 4 + r] = acc1[r];
        }
    }
    __syncthreads();

    for (int gh = 0; gh < 2; gh++) {
        int colb = gh * 16;
        if (w < 3) {
            s16x8 a_h1, a_m;
            #pragma unroll
            for (int e = 0; e < 8; e++) {
                int k = kg * 8 + e;
                a_h1[e] = (short)f2bf(AL[k * 33 + colb + j]);
                a_m[e]  = (short)f2bf(AL[(32 + k) * 33 + colb + j]);
            }
            const uint16_t* WpG = Wp + 4 * 64 * 64;   // gate-pairs 4..6 (gates 8..13)
            const float*    bG  = bf_ + 512;
            int p = w;
            int g0 = p * 2, g1 = p * 2 + 1;           // even: ah1, odd: am
            f32x4 ac0[4] = {}, ac1[4] = {};
            #pragma unroll
            for (int ct = 0; ct < 4; ct++) {
                int col = ct * 16 + j;
                int ph0 = (kg)     ^ (col & 7);
                int ph1 = (4 + kg) ^ (col & 7);
                s16x8 b0 = *(const s16x8*)(WpG + (p * 64 + col) * 64 + ph0 * 8);
                s16x8 b1 = *(const s16x8*)(WpG + (p * 64 + col) * 64 + ph1 * 8);
                ac0[ct] = __builtin_amdgcn_mfma_f32_16x16x32_bf16(a_h1, b0, ac0[ct], 0, 0, 0);
                ac1[ct] = __builtin_amdgcn_mfma_f32_16x16x32_bf16(a_m, b1, ac1[ct], 0, 0, 0);
            }
            #pragma unroll
            for (int hh = 0; hh < 2; hh++)
                #pragma unroll
                for (int r = 0; r < 4; r++) {
                    float z0l = ac0[hh][r]     + bG[g0 * 64 + hh * 16 + j];
                    float z0r = ac0[2 + hh][r] + bG[g0 * 64 + 32 + hh * 16 + j];
                    float z1l = ac1[hh][r]     + bG[g1 * 64 + hh * 16 + j];
                    float z1r = ac1[2 + hh][r] + bG[g1 * 64 + 32 + hh * 16 + j];
                    SX[p][lane][hh * 4 + r] = z0l * sig_acc(z0r) + z1l * sig_acc(z1r);
                }
        }
        __syncthreads();
        {
            int pl = ((erow >> 2) << 4) | ej;
            int ridx = erow & 3;
            #pragma unroll
            for (int hh = 0; hh < 2; hh++) {
                float s0 = SX[0][pl][hh * 4 + ridx];
                float s1 = SX[1][pl][hh * 4 + ridx];
                float s2 = SX[2][pl][hh * 4 + ridx];
                float i2 = sig_acc(s0);
                float gg = sig_acc(s1);
                float o2 = sig_acc(s2);
                float mn = i2 * mv[gh][hh] + (1.0f - i2) * gg;
                size_t gidx = ((size_t)(b * NN + n0 + gh * 16 + erow)) * FF + ej + hh * 16;
                mnew[gidx] = mn;
                hnew[gidx] = mn * o2;
            }
        }
        __syncthreads();
    }
}

extern "C" void kernel_launch(void* const* d_in, const int* in_sizes, int n_in,
                              void* d_out, int out_size, void* d_ws, size_t ws_size,
                              hipStream_t stream) {
    (void)in_sizes; (void)n_in; (void)out_size;
    const float* x   = (const float*)d_in[0];
    const float* h   = (const float*)d_in[1];
    const float* c   = (const float*)d_in[2];
    const float* m   = (const float*)d_in[3];
    const float* adj = (const float*)d_in[4];
    const float* W   = (const float*)d_in[5];
    const float* bb  = (const float*)d_in[6];
    float* out = (float*)d_out;

    char* ws = (char*)d_ws;
    // tier A (ws >= 40MB): bf16 adj copy + global_load_lds A staging;
    // tier B: fp32 reg-staging straight from adj.
    int haveAdjb = ws_size >= (size_t)(40u << 20);
    uint16_t* adjb = (uint16_t*)ws;                              // 32 MB (tier A)
    size_t pOff = haveAdjb ? (size_t)(32u << 20) : 0;
    uint16_t* P    = (uint16_t*)(ws + pOff);                     // 2 MB phase-1 B (x,h)
    uint16_t* P2   = (uint16_t*)(ws + pOff + (2u << 20));        // 2 MB phase-2 B (h1,m)
    uint16_t* Wp   = (uint16_t*)(ws + pOff + (4u << 20));        // 112 KB packed W

    if (ws_size < (6u << 20)) return;   // harness ws is ~268MB; safety only

    const void* Agemm = haveAdjb ? (const void*)adjb : (const void*)adj;
    int isf32A = haveAdjb ? 0 : 1;
    int cvtN = haveAdjb ? 8192 : 0;

    // ONE prep launch: adj->bf16, W pack, x/h -> P, m -> P2 (all input-only)
    prep_kernel<<<cvtN + 112 + 768, 256, 0, stream>>>(adj, adjb, cvtN, W, Wp, x, h, m, P, P2);

    // phase 1: GEMM(adj x P) + GLU + LSTM; c_new + h1 -> P2 rows 0..127
    mega1_kernel<<<512, 256, 0, stream>>>(Agemm, P, Wp, bb, c, out + BNF, P2, isf32A);
    // phase 2: GEMM(adj x P2) + GLU + memory update; h_new, m_new
    mega2_kernel<<<512, 256, 0, stream>>>(Agemm, P2, Wp, bb, m, out, out + 2 * BNF, isf32A);
}

// Round 13
// 171.023 us; speedup vs baseline: 1.4317x; 1.0111x over previous
//
#include <hip/hip_runtime.h>
#include <stdint.h>

typedef __attribute__((ext_vector_type(4))) float f32x4;
typedef __attribute__((ext_vector_type(8))) short s16x8;

#define BB 4
#define NN 4096
#define FF 32
#define BNF (BB*NN*FF)   // 524288

typedef __attribute__((address_space(3))) void       as3_void;
typedef const __attribute__((address_space(1))) void as1_cvoid;

// ---------- bf16 helpers ----------
static __device__ __forceinline__ float bf2f(uint16_t u) {
    union { uint32_t i; float f; } v; v.i = ((uint32_t)u) << 16; return v.f;
}
static __device__ __forceinline__ uint16_t f2bf(float f) {
    union { float f; uint32_t i; } v; v.f = f;
    uint32_t r = v.i + 0x7FFFu + ((v.i >> 16) & 1u);
    return (uint16_t)(r >> 16);
}
static __device__ __forceinline__ float sig_acc(float x) { return 1.0f / (1.0f + expf(-x)); }

// ======================================================================
// prep: ONE launch for all input-only work (R7-validated structure).
// ======================================================================
__global__ __launch_bounds__(256) void prep_kernel(
    const float* __restrict__ adj, uint16_t* __restrict__ adjb, int cvtN,
    const float* __restrict__ Wf, uint16_t* __restrict__ Wp,
    const float* __restrict__ x, const float* __restrict__ h,
    const float* __restrict__ m,
    uint16_t* __restrict__ P, uint16_t* __restrict__ P2)
{
    int bid = blockIdx.x;
    int t = threadIdx.x;

    if (bid < cvtN) {
        size_t i = ((size_t)bid * 256 + t) * 8;
        float4 v0 = *(const float4*)(adj + i);
        float4 v1 = *(const float4*)(adj + i + 4);
        union { uint4 u; uint16_t e[8]; } o;
        o.e[0] = f2bf(v0.x); o.e[1] = f2bf(v0.y); o.e[2] = f2bf(v0.z); o.e[3] = f2bf(v0.w);
        o.e[4] = f2bf(v1.x); o.e[5] = f2bf(v1.y); o.e[6] = f2bf(v1.z); o.e[7] = f2bf(v1.w);
        *(uint4*)(adjb + i) = o.u;
        return;
    }
    bid -= cvtN;

    if (bid < 112) {
        // W: fp32 [14][32][64] -> bf16 Wp[gp][col][slot^swz][k&7]
        int idx = bid * 256 + t;                    // 14*32*64 = 28672
        int g   = idx >> 11;
        int k   = (idx >> 6) & 31;
        int col = idx & 63;
        uint16_t v = f2bf(Wf[idx]);                 // Wf[g][k][col]
        int gp = g >> 1;
        int sl = ((g & 1) << 2) | (k >> 3);
        int ph = sl ^ (col & 7);
        Wp[((gp * 64 + col) * 64) + ph * 8 + (k & 7)] = v;
        return;
    }
    bid -= 112;

    // pack: state [B][N][F] fp32 -> dst[rowbase + b*32 + f][n] bf16
    const float* src; uint16_t* dst; int rowbase, b, n0;
    if (bid < 512) {
        int tensor = bid >> 8;
        src = tensor ? h : x; dst = P; rowbase = tensor * 128;
        b = (bid >> 6) & 3; n0 = (bid & 63) * 64;
    } else {
        int q = bid - 512;
        src = m; dst = P2; rowbase = 128;
        b = q >> 6; n0 = (q & 63) * 64;
    }
    __shared__ uint16_t tl[32][65];
    {
        int i = t >> 2, ch = t & 3;       // node i (0..63), f-chunk ch (8 floats)
        size_t idx = ((size_t)(b * NN + n0 + i)) * FF + ch * 8;
        float4 v0 = *(const float4*)(src + idx);
        float4 v1 = *(const float4*)(src + idx + 4);
        uint16_t e[8] = { f2bf(v0.x), f2bf(v0.y), f2bf(v0.z), f2bf(v0.w),
                          f2bf(v1.x), f2bf(v1.y), f2bf(v1.z), f2bf(v1.w) };
        #pragma unroll
        for (int k = 0; k < 8; k++) tl[ch * 8 + k][i] = e[k];
    }
    __syncthreads();
    {
        int f = t >> 3, ch = t & 7;
        union { uint4 u; uint16_t e[8]; } v;
        #pragma unroll
        for (int k = 0; k < 8; k++) v.e[k] = tl[f][ch * 8 + k];
        size_t row = (size_t)(rowbase + b * 32 + f);
        *(uint4*)(dst + row * NN + n0 + ch * 8) = v.u;
    }
}

// ======================================================================
// mega1: GEMM (adj x P, full K=4096) + dense(MFMA) + GLU + LSTM.
// Block = (batch b, 32 nodes); 512 blocks (2/CU).
// Tier-A K-loop: 2-phase counted-vmcnt pipeline (double-buffered staging;
// issue tile i+1's 6 global_load_lds, s_waitcnt vmcnt(6), RAW s_barrier,
// compute tile i, barrier).  Never drains vmcnt to 0 in the main loop —
// hides L2/L3 latency under the previous tile's ds_read+MFMA.
// Staging/swizzle/ds_read/MFMA formulas byte-identical to validated R12.
// Tier-B (fp32 adj) keeps the R12 drain loop (reg-staging breaks counting).
// ======================================================================
__global__ __launch_bounds__(256, 2) void mega1_kernel(
    const void* __restrict__ Av,      // adj: bf16 (isf32A=0) or fp32 (isf32A=1)
    const uint16_t* __restrict__ P,   // [256][4096] bf16 (x 0..127, h 128..255)
    const uint16_t* __restrict__ Wp,  // packed W (prep)
    const float* __restrict__ bf_,
    const float* __restrict__ cf,
    float* __restrict__ cnew, uint16_t* __restrict__ S2t, int isf32A)
{
    __shared__ __align__(16) uint16_t aLb[2][4][32 * 32];  // 16 KB
    __shared__ __align__(16) uint16_t bLb[2][4][64 * 32];  // 32 KB
    __shared__ float    AL[64 * 33];                       // 8.4 KB
    __shared__ float    SX[4][64][9];                      // 9.2 KB
    __shared__ uint16_t H1[32 * 18];                       // 1.2 KB

    int t = threadIdx.x;
    int bid = blockIdx.x;              // 512
    int b = bid >> 7, n0 = (bid & 127) * 32;
    int lane = t & 63, w = t >> 6;
    int lm = lane & 15, lk = lane >> 4;
    int j = lm, kg = lk;
    int ej = t & 15, erow = (t >> 4) & 15;

    const uint16_t* A16 = (const uint16_t*)Av;
    const float*    Af  = (const float*)Av;

    // c prefetch — issued OLDEST, drained by the first counted wait
    float cv[2][2];
    #pragma unroll
    for (int gh = 0; gh < 2; gh++)
        #pragma unroll
        for (int hh = 0; hh < 2; hh++)
            cv[gh][hh] = cf[((size_t)(b * NN + n0 + gh * 16 + erow)) * FF + ej + hh * 16];

    // A slot constants: 2 slots/thread (4 bufs x 32 rows x 4 slots = 512)
    int aq0 = t >> 7,        ap0 = (t & 127) * 16;
    int ar0 = ap0 >> 6,      asl0 = ((ap0 >> 4) & 3) ^ ((ar0 >> 1) & 3);
    int gs1 = t + 256;
    int aq1 = gs1 >> 7,      ap1 = (gs1 & 127) * 16;
    int ar1 = ap1 >> 6,      asl1 = ((ap1 >> 4) & 3) ^ ((ar1 >> 1) & 3);
    // B constants (verbatim R12)
    int bpos = t * 16;
    int brow = bpos >> 6;
    int bslot = ((bpos >> 4) & 3) ^ ((brow >> 1) & 3);
    int bcrow = brow + ((brow < 32) ? b * 32 : 96 + b * 32);  // 128+b*32+(brow-32)
    int rB = w * 16 + lm; int swB = (lk ^ ((rB >> 1) & 3)) * 8;
    int swA = (lk ^ ((lm >> 1) & 3)) * 8;     // same for node halves 0..15 / 16..31

    f32x4 acc0 = {}, acc1 = {};

    if (!isf32A) {
        // ---------------- 2-phase counted-vmcnt pipeline ----------------
        #define ISSUE1(kk, d)                                                          \
        {                                                                              \
            __builtin_amdgcn_global_load_lds(                                          \
                (as1_cvoid*)(A16 + (size_t)(n0 + ar0) * 4096 + (kk) + aq0 * 32 + asl0 * 8), \
                (as3_void*)((char*)aLb[d][aq0] + ap0), 16, 0, 0);                      \
            __builtin_amdgcn_global_load_lds(                                          \
                (as1_cvoid*)(A16 + (size_t)(n0 + ar1) * 4096 + (kk) + aq1 * 32 + asl1 * 8), \
                (as3_void*)((char*)aLb[d][aq1] + ap1), 16, 0, 0);                      \
            _Pragma("unroll")                                                          \
            for (int q = 0; q < 4; q++)                                                \
                __builtin_amdgcn_global_load_lds(                                      \
                    (as1_cvoid*)(P + (size_t)bcrow * 4096 + (kk) + q * 32 + bslot * 8),\
                    (as3_void*)((char*)bLb[d][q] + bpos), 16, 0, 0);                   \
        }
        #define COMPUTE1(d)                                                            \
        {                                                                              \
            _Pragma("unroll")                                                          \
            for (int q = 0; q < 4; q++) {                                              \
                s16x8 af0 = *(const s16x8*)(aLb[d][q] + lm * 32 + swA);                \
                s16x8 af1 = *(const s16x8*)(aLb[d][q] + (16 + lm) * 32 + swA);         \
                s16x8 bf  = *(const s16x8*)(bLb[d][q] + rB * 32 + swB);                \
                acc0 = __builtin_amdgcn_mfma_f32_16x16x32_bf16(af0, bf, acc0, 0, 0, 0);\
                acc1 = __builtin_amdgcn_mfma_f32_16x16x32_bf16(af1, bf, acc1, 0, 0, 0);\
            }                                                                          \
        }
        ISSUE1(0, 0);
        int cur = 0;
        for (int it = 0; it < 31; ++it) {
            ISSUE1((it + 1) << 7, cur ^ 1);
            asm volatile("s_waitcnt vmcnt(6)" ::: "memory");
            __builtin_amdgcn_s_barrier();
            COMPUTE1(cur);
            __builtin_amdgcn_s_barrier();
            cur ^= 1;
        }
        asm volatile("s_waitcnt vmcnt(0)" ::: "memory");
        __builtin_amdgcn_s_barrier();
        COMPUTE1(cur);
        #undef ISSUE1
        #undef COMPUTE1
    } else {
        // ---------------- R12 drain loop (fp32 A reg-staging) ----------------
        for (int kk = 0; kk < 4096; kk += 128) {
            union { uint4 u; uint16_t e[8]; } sa0, sa1;
            {
                size_t aidx = (size_t)(n0 + ar0) * 4096 + kk + aq0 * 32 + asl0 * 8;
                union { uint4 u[2]; float f[8]; } va;
                va.u[0] = *(const uint4*)(Af + aidx);
                va.u[1] = *(const uint4*)(Af + aidx + 4);
                #pragma unroll
                for (int k = 0; k < 8; k++) sa0.e[k] = f2bf(va.f[k]);
            }
            {
                size_t aidx = (size_t)(n0 + ar1) * 4096 + kk + aq1 * 32 + asl1 * 8;
                union { uint4 u[2]; float f[8]; } va;
                va.u[0] = *(const uint4*)(Af + aidx);
                va.u[1] = *(const uint4*)(Af + aidx + 4);
                #pragma unroll
                for (int k = 0; k < 8; k++) sa1.e[k] = f2bf(va.f[k]);
            }
            *(uint4*)((char*)aLb[0][aq0] + ap0) = sa0.u;
            *(uint4*)((char*)aLb[0][aq1] + ap1) = sa1.u;
            #pragma unroll
            for (int q = 0; q < 4; q++) {
                size_t bidx = (size_t)bcrow * 4096 + kk + q * 32 + bslot * 8;
                union { uint4 u; } sb;
                sb.u = *(const uint4*)(P + bidx);
                *(uint4*)((char*)bLb[0][q] + bpos) = sb.u;
            }
            __syncthreads();
            #pragma unroll
            for (int q = 0; q < 4; q++) {
                s16x8 af0 = *(const s16x8*)(aLb[0][q] + lm * 32 + swA);
                s16x8 af1 = *(const s16x8*)(aLb[0][q] + (16 + lm) * 32 + swA);
                s16x8 bf  = *(const s16x8*)(bLb[0][q] + rB * 32 + swB);
                acc0 = __builtin_amdgcn_mfma_f32_16x16x32_bf16(af0, bf, acc0, 0, 0, 0);
                acc1 = __builtin_amdgcn_mfma_f32_16x16x32_bf16(af1, bf, acc1, 0, 0, 0);
            }
            __syncthreads();
        }
    }

    // scatter acc -> AL[c'][node 0..31]
    __syncthreads();
    {
        int cp = w * 16 + lm;
        #pragma unroll
        for (int r = 0; r < 4; r++) {
            AL[cp * 33 + lk * 4 + r]      = acc0[r];
            AL[cp * 33 + 16 + lk * 4 + r] = acc1[r];
        }
    }
    __syncthreads();

    // ---- fuse phase 2/3 per 16-node half (verbatim validated fuse1) ----
    for (int gh = 0; gh < 2; gh++) {
        int colb = gh * 16;
        s16x8 a_ax, a_ah;
        #pragma unroll
        for (int e = 0; e < 8; e++) {
            int k = kg * 8 + e;
            a_ax[e] = (short)f2bf(AL[k * 33 + colb + j]);
            a_ah[e] = (short)f2bf(AL[(32 + k) * 33 + colb + j]);
        }
        {
            int p = w;                                // gate-pair: even=ax, odd=ah
            int g0 = p * 2, g1 = p * 2 + 1;
            f32x4 ac0[4] = {}, ac1[4] = {};
            #pragma unroll
            for (int ct = 0; ct < 4; ct++) {
                int col = ct * 16 + j;
                int ph0 = (kg)     ^ (col & 7);
                int ph1 = (4 + kg) ^ (col & 7);
                s16x8 b0 = *(const s16x8*)(Wp + (p * 64 + col) * 64 + ph0 * 8);
                s16x8 b1 = *(const s16x8*)(Wp + (p * 64 + col) * 64 + ph1 * 8);
                ac0[ct] = __builtin_amdgcn_mfma_f32_16x16x32_bf16(a_ax, b0, ac0[ct], 0, 0, 0);
                ac1[ct] = __builtin_amdgcn_mfma_f32_16x16x32_bf16(a_ah, b1, ac1[ct], 0, 0, 0);
            }
            #pragma unroll
            for (int hh = 0; hh < 2; hh++)
                #pragma unroll
                for (int r = 0; r < 4; r++) {
                    float z0l = ac0[hh][r]     + bf_[g0 * 64 + hh * 16 + j];
                    float z0r = ac0[2 + hh][r] + bf_[g0 * 64 + 32 + hh * 16 + j];
                    float z1l = ac1[hh][r]     + bf_[g1 * 64 + hh * 16 + j];
                    float z1r = ac1[2 + hh][r] + bf_[g1 * 64 + 32 + hh * 16 + j];
                    SX[p][lane][hh * 4 + r] = z0l * sig_acc(z0r) + z1l * sig_acc(z1r);
                }
        }
        __syncthreads();
        {
            int pl = ((erow >> 2) << 4) | ej;         // producer lane
            int ridx = erow & 3;
            #pragma unroll
            for (int hh = 0; hh < 2; hh++) {
                float s0 = SX[0][pl][hh * 4 + ridx];
                float s1 = SX[1][pl][hh * 4 + ridx];
                float s2 = SX[2][pl][hh * 4 + ridx];
                float s3 = SX[3][pl][hh * 4 + ridx];
                float fg = sig_acc(s0), ig = sig_acc(s1);
                float cc = tanhf(s2),   og = sig_acc(s3);
                float cn = fg * cv[gh][hh] + ig * cc;
                size_t gidx = ((size_t)(b * NN + n0 + gh * 16 + erow)) * FF + ej + hh * 16;
                cnew[gidx] = cn;
                H1[(ej + hh * 16) * 18 + erow] = f2bf(og * tanhf(cn));
            }
        }
        __syncthreads();
        if (t < 64) {   // pack h1 -> P2 rows b*32+f (phase-2 B operand)
            int f = t >> 1, half = t & 1;
            union { uint4 u; uint16_t e[8]; } v;
            #pragma unroll
            for (int k = 0; k < 8; k++) v.e[k] = H1[f * 18 + half * 8 + k];
            *(uint4*)(S2t + ((size_t)(b * 32 + f)) * NN + n0 + gh * 16 + half * 8) = v.u;
        }
        __syncthreads();
    }
}

// ======================================================================
// mega2: same pipelined K-loop (B = P2: h1 rows 0..127, m rows 128..255)
// + fuse2 phase 2/3 per half (3 gate-pairs; wave 3 idles in the W-MFMA).
// ======================================================================
__global__ __launch_bounds__(256, 2) void mega2_kernel(
    const void* __restrict__ Av,
    const uint16_t* __restrict__ P2,
    const uint16_t* __restrict__ Wp,
    const float* __restrict__ bf_,
    const float* __restrict__ mf,
    float* __restrict__ hnew, float* __restrict__ mnew, int isf32A)
{
    __shared__ __align__(16) uint16_t aLb[2][4][32 * 32];
    __shared__ __align__(16) uint16_t bLb[2][4][64 * 32];
    __shared__ float AL[64 * 33];
    __shared__ float SX[3][64][9];

    int t = threadIdx.x;
    int bid = blockIdx.x;              // 512
    int b = bid >> 7, n0 = (bid & 127) * 32;
    int lane = t & 63, w = t >> 6;
    int lm = lane & 15, lk = lane >> 4;
    int j = lm, kg = lk;
    int ej = t & 15, erow = (t >> 4) & 15;

    const uint16_t* A16 = (const uint16_t*)Av;
    const float*    Af  = (const float*)Av;

    float mv[2][2];
    #pragma unroll
    for (int gh = 0; gh < 2; gh++)
        #pragma unroll
        for (int hh = 0; hh < 2; hh++)
            mv[gh][hh] = mf[((size_t)(b * NN + n0 + gh * 16 + erow)) * FF + ej + hh * 16];

    int aq0 = t >> 7,        ap0 = (t & 127) * 16;
    int ar0 = ap0 >> 6,      asl0 = ((ap0 >> 4) & 3) ^ ((ar0 >> 1) & 3);
    int gs1 = t + 256;
    int aq1 = gs1 >> 7,      ap1 = (gs1 & 127) * 16;
    int ar1 = ap1 >> 6,      asl1 = ((ap1 >> 4) & 3) ^ ((ar1 >> 1) & 3);
    int bpos = t * 16;
    int brow = bpos >> 6;
    int bslot = ((bpos >> 4) & 3) ^ ((brow >> 1) & 3);
    int bcrow = brow + ((brow < 32) ? b * 32 : 96 + b * 32);
    int rB = w * 16 + lm; int swB = (lk ^ ((rB >> 1) & 3)) * 8;
    int swA = (lk ^ ((lm >> 1) & 3)) * 8;

    f32x4 acc0 = {}, acc1 = {};

    if (!isf32A) {
        #define ISSUE2(kk, d)                                                          \
        {                                                                              \
            __builtin_amdgcn_global_load_lds(                                          \
                (as1_cvoid*)(A16 + (size_t)(n0 + ar0) * 4096 + (kk) + aq0 * 32 + asl0 * 8), \
                (as3_void*)((char*)aLb[d][aq0] + ap0), 16, 0, 0);                      \
            __builtin_amdgcn_global_load_lds(                                          \
                (as1_cvoid*)(A16 + (size_t)(n0 + ar1) * 4096 + (kk) + aq1 * 32 + asl1 * 8), \
                (as3_void*)((char*)aLb[d][aq1] + ap1), 16, 0, 0);                      \
            _Pragma("unroll")                                                          \
            for (int q = 0; q < 4; q++)                                                \
                __builtin_amdgcn_global_load_lds(                                      \
                    (as1_cvoid*)(P2 + (size_t)bcrow * 4096 + (kk) + q * 32 + bslot * 8),\
                    (as3_void*)((char*)bLb[d][q] + bpos), 16, 0, 0);                   \
        }
        #define COMPUTE2(d)                                                            \
        {                                                                              \
            _Pragma("unroll")                                                          \
            for (int q = 0; q < 4; q++) {                                              \
                s16x8 af0 = *(const s16x8*)(aLb[d][q] + lm * 32 + swA);                \
                s16x8 af1 = *(const s16x8*)(aLb[d][q] + (16 + lm) * 32 + swA);         \
                s16x8 bf  = *(const s16x8*)(bLb[d][q] + rB * 32 + swB);                \
                acc0 = __builtin_amdgcn_mfma_f32_16x16x32_bf16(af0, bf, acc0, 0, 0, 0);\
                acc1 = __builtin_amdgcn_mfma_f32_16x16x32_bf16(af1, bf, acc1, 0, 0, 0);\
            }                                                                          \
        }
        ISSUE2(0, 0);
        int cur = 0;
        for (int it = 0; it < 31; ++it) {
            ISSUE2((it + 1) << 7, cur ^ 1);
            asm volatile("s_waitcnt vmcnt(6)" ::: "memory");
            __builtin_amdgcn_s_barrier();
            COMPUTE2(cur);
            __builtin_amdgcn_s_barrier();
            cur ^= 1;
        }
        asm volatile("s_waitcnt vmcnt(0)" ::: "memory");
        __builtin_amdgcn_s_barrier();
        COMPUTE2(cur);
        #undef ISSUE2
        #undef COMPUTE2
    } else {
        for (int kk = 0; kk < 4096; kk += 128) {
            union { uint4 u; uint16_t e[8]; } sa0, sa1;
            {
                size_t aidx = (size_t)(n0 + ar0) * 4096 + kk + aq0 * 32 + asl0 * 8;
                union { uint4 u[2]; float f[8]; } va;
                va.u[0] = *(const uint4*)(Af + aidx);
                va.u[1] = *(const uint4*)(Af + aidx + 4);
                #pragma unroll
                for (int k = 0; k < 8; k++) sa0.e[k] = f2bf(va.f[k]);
            }
            {
                size_t aidx = (size_t)(n0 + ar1) * 4096 + kk + aq1 * 32 + asl1 * 8;
                union { uint4 u[2]; float f[8]; } va;
                va.u[0] = *(const uint4*)(Af + aidx);
                va.u[1] = *(const uint4*)(Af + aidx + 4);
                #pragma unroll
                for (int k = 0; k < 8; k++) sa1.e[k] = f2bf(va.f[k]);
            }
            *(uint4*)((char*)aLb[0][aq0] + ap0) = sa0.u;
            *(uint4*)((char*)aLb[0][aq1] + ap1) = sa1.u;
            #pragma unroll
            for (int q = 0; q < 4; q++) {
                size_t bidx = (size_t)bcrow * 4096 + kk + q * 32 + bslot * 8;
                union { uint4 u; } sb;
                sb.u = *(const uint4*)(P2 + bidx);
                *(uint4*)((char*)bLb[0][q] + bpos) = sb.u;
            }
            __syncthreads();
            #pragma unroll
            for (int q = 0; q < 4; q++) {
                s16x8 af0 = *(const s16x8*)(aLb[0][q] + lm * 32 + swA);
                s16x8 af1 = *(const s16x8*)(aLb[0][q] + (16 + lm) * 32 + swA);
                s16x8 bf  = *(const s16x8*)(bLb[0][q] + rB * 32 + swB);
                acc0 = __builtin_amdgcn_mfma_f32_16x16x32_bf16(af0, bf, acc0, 0, 0, 0);
                acc1 = __builtin_amdgcn_mfma_f32_16x16x32_bf16(af1, bf, acc1, 0, 0, 0);
            }
            __syncthreads();
        }
    }

    __syncthreads();
    {
        int cp = w * 16 + lm;
        #pragma unroll
        for (int r = 0; r < 4; r++) {
            AL[cp * 33 + lk * 4 + r]      = acc0[r];
            AL[cp * 33 + 16 + lk * 4 + r] = acc1[r];
        }
    }
    __syncthreads();

    for (int gh = 0; gh < 2; gh++) {
        int colb = gh * 16;
        if (w < 3) {
            s16x8 a_h1, a_m;
            #pragma unroll
            for (int e = 0; e < 8; e++) {
                int k = kg * 8 + e;
                a_h1[e] = (short)f2bf(AL[k * 33 + colb + j]);
                a_m[e]  = (short)f2bf(AL[(32 + k) * 33 + colb + j]);
            }
            const uint16_t* WpG = Wp + 4 * 64 * 64;   // gate-pairs 4..6 (gates 8..13)
            const float*    bG  = bf_ + 512;
            int p = w;
            int g0 = p * 2, g1 = p * 2 + 1;           // even: ah1, odd: am
            f32x4 ac0[4] = {}, ac1[4] = {};
            #pragma unroll
            for (int ct = 0; ct < 4; ct++) {
                int col = ct * 16 + j;
                int ph0 = (kg)     ^ (col & 7);
                int ph1 = (4 + kg) ^ (col & 7);
                s16x8 b0 = *(const s16x8*)(WpG + (p * 64 + col) * 64 + ph0 * 8);
                s16x8 b1 = *(const s16x8*)(WpG + (p * 64 + col) * 64 + ph1 * 8);
                ac0[ct] = __builtin_amdgcn_mfma_f32_16x16x32_bf16(a_h1, b0, ac0[ct], 0, 0, 0);
                ac1[ct] = __builtin_amdgcn_mfma_f32_16x16x32_bf16(a_m, b1, ac1[ct], 0, 0, 0);
            }
            #pragma unroll
            for (int hh = 0; hh < 2; hh++)
                #pragma unroll
                for (int r = 0; r < 4; r++) {
                    float z0l = ac0[hh][r]     + bG[g0 * 64 + hh * 16 + j];
                    float z0r = ac0[2 + hh][r] + bG[g0 * 64 + 32 + hh * 16 + j];
                    float z1l = ac1[hh][r]     + bG[g1 * 64 + hh * 16 + j];
                    float z1r = ac1[2 + hh][r] + bG[g1 * 64 + 32 + hh * 16 + j];
                    SX[p][lane][hh * 4 + r] = z0l * sig_acc(z0r) + z1l * sig_acc(z1r);
                }
        }
        __syncthreads();
        {
            int pl = ((erow >> 2) << 4) | ej;
            int ridx = erow & 3;
            #pragma unroll
            for (int hh = 0; hh < 2; hh++) {
                float s0 = SX[0][pl][hh * 4 + ridx];
                float s1 = SX[1][pl][hh * 4 + ridx];
                float s2 = SX[2][pl][hh * 4 + ridx];
                float i2 = sig_acc(s0);
                float gg = sig_acc(s1);
                float o2 = sig_acc(s2);
                float mn = i2 * mv[gh][hh] + (1.0f - i2) * gg;
                size_t gidx = ((size_t)(b * NN + n0 + gh * 16 + erow)) * FF + ej + hh * 16;
                mnew[gidx] = mn;
                hnew[gidx] = mn * o2;
            }
        }
        __syncthreads();
    }
}

extern "C" void kernel_launch(void* const* d_in, const int* in_sizes, int n_in,
                              void* d_out, int out_size, void* d_ws, size_t ws_size,
                              hipStream_t stream) {
    (void)in_sizes; (void)n_in; (void)out_size;
    const float* x   = (const float*)d_in[0];
    const float* h   = (const float*)d_in[1];
    const float* c   = (const float*)d_in[2];
    const float* m   = (const float*)d_in[3];
    const float* adj = (const float*)d_in[4];
    const float* W   = (const float*)d_in[5];
    const float* bb  = (const float*)d_in[6];
    float* out = (float*)d_out;

    char* ws = (char*)d_ws;
    // tier A (ws >= 40MB): bf16 adj copy + global_load_lds A staging;
    // tier B: fp32 reg-staging straight from adj.
    int haveAdjb = ws_size >= (size_t)(40u << 20);
    uint16_t* adjb = (uint16_t*)ws;                              // 32 MB (tier A)
    size_t pOff = haveAdjb ? (size_t)(32u << 20) : 0;
    uint16_t* P    = (uint16_t*)(ws + pOff);                     // 2 MB phase-1 B (x,h)
    uint16_t* P2   = (uint16_t*)(ws + pOff + (2u << 20));        // 2 MB phase-2 B (h1,m)
    uint16_t* Wp   = (uint16_t*)(ws + pOff + (4u << 20));        // 112 KB packed W

    if (ws_size < (6u << 20)) return;   // harness ws is ~268MB; safety only

    const void* Agemm = haveAdjb ? (const void*)adjb : (const void*)adj;
    int isf32A = haveAdjb ? 0 : 1;
    int cvtN = haveAdjb ? 8192 : 0;

    // ONE prep launch: adj->bf16, W pack, x/h -> P, m -> P2 (all input-only)
    prep_kernel<<<cvtN + 112 + 768, 256, 0, stream>>>(adj, adjb, cvtN, W, Wp, x, h, m, P, P2);

    // phase 1: GEMM(adj x P) + GLU + LSTM; c_new + h1 -> P2 rows 0..127
    mega1_kernel<<<512, 256, 0, stream>>>(Agemm, P, Wp, bb, c, out + BNF, P2, isf32A);
    // phase 2: GEMM(adj x P2) + GLU + memory update; h_new, m_new
    mega2_kernel<<<512, 256, 0, stream>>>(Agemm, P2, Wp, bb, m, out, out + 2 * BNF, isf32A);
}